// Round 10
// baseline (341.389 us; speedup 1.0000x reference)
//
#include <hip/hip_runtime.h>
#include <hip/hip_bf16.h>
#include <cstdint>
#include <cstddef>

#define B_   2
#define C_   512
#define N_   4096
#define NH   4
#define DH_  32
#define HID  128
#define LOG2E 1.4426950408889634f

typedef __attribute__((ext_vector_type(8))) short bf16x8;
typedef __attribute__((ext_vector_type(4))) float f32x4;

#if __has_builtin(__builtin_amdgcn_exp2f)
#define EXP2(x) __builtin_amdgcn_exp2f(x)
#else
#define EXP2(x) exp2f(x)
#endif

static __device__ __forceinline__ unsigned short f2bf(float f) {
  union { float f; unsigned int u; } v; v.f = f;
  unsigned int r = v.u + 0x7fffu + ((v.u >> 16) & 1u);
  return (unsigned short)(r >> 16);
}

static __device__ __forceinline__ float sbc(float x) {  // force to SGPR
  return __uint_as_float(__builtin_amdgcn_readfirstlane(__float_as_uint(x)));
}

// ---------------------------------------------------------------------------
// Prep A: convert wq|wk|wv (f32 [128][512] each) -> wbf bf16 [384][512]
// ---------------------------------------------------------------------------
__global__ __launch_bounds__(256)
void prep_w(const float* __restrict__ wq, const float* __restrict__ wk,
            const float* __restrict__ wv, unsigned short* __restrict__ wbf)
{
  int gid  = blockIdx.x * 256 + threadIdx.x;
  int elem = gid * 4;
  int t    = elem >> 16;                 // 65536 elems per tensor
  int off  = elem & 65535;
  const float* src = (t == 0) ? wq : (t == 1) ? wk : wv;
  float4 v = *(const float4*)(src + off);
  alignas(8) unsigned short tmp[4];
  tmp[0] = f2bf(v.x); tmp[1] = f2bf(v.y); tmp[2] = f2bf(v.z); tmp[3] = f2bf(v.w);
  *(uint2*)(wbf + t * 65536 + off) = *(const uint2*)tmp;
}

// ---------------------------------------------------------------------------
// Prep B: transpose-convert x f32 [b][c][n] -> xT bf16 [b][n][c]
// ---------------------------------------------------------------------------
__global__ __launch_bounds__(256)
void prep_xt(const float* __restrict__ x, unsigned short* __restrict__ xT)
{
  int bid = blockIdx.x;
  int b   = bid >> 9;
  int rem = bid & 511;
  int ct  = rem >> 6;
  int nt  = rem & 63;
  int c0  = ct << 6;
  int n0  = nt << 6;

  int tid = threadIdx.x;
  __shared__ float xs[64][65];

  const float* xb = x + (size_t)b * C_ * N_;
#pragma unroll
  for (int rr = 0; rr < 16; rr++) {
    int row = (tid >> 6) * 16 + rr;
    xs[row][tid & 63] = xb[(size_t)(c0 + row) * N_ + n0 + (tid & 63)];
  }
  __syncthreads();

  int cseg = (tid & 7) * 8;
#pragma unroll
  for (int pass = 0; pass < 2; pass++) {
    int nrow = pass * 32 + (tid >> 3);
    alignas(16) unsigned short tmp[8];
#pragma unroll
    for (int j = 0; j < 8; j++) tmp[j] = f2bf(xs[cseg + j][nrow]);
    *(uint4*)(xT + ((size_t)b * N_ + n0 + nrow) * C_ + c0 + cseg) = *(const uint4*)tmp;
  }
}

// ---------------------------------------------------------------------------
// Kernel 1: QKV projection as MFMA GEMM. M=384, N=8192, K=512.
// ---------------------------------------------------------------------------
__global__ __launch_bounds__(256)
void qkv_gemm(const unsigned short* __restrict__ wbf,
              const unsigned short* __restrict__ xT,
              const float* __restrict__ bq, const float* __restrict__ bk,
              const float* __restrict__ bv,
              unsigned short* __restrict__ qws,
              unsigned short* __restrict__ kws,
              unsigned short* __restrict__ vtws)
{
  int bid = blockIdx.x;
  int ot  = bid % 6;
  int ntl = bid / 6;                 // 0..127
  int b   = ntl >> 6;
  int n0  = (ntl & 63) << 6;
  int o0  = ot << 6;                 // 0..320
  int t   = o0 >> 7;                 // tensor 0=q 1=k 2=v

  int tid = threadIdx.x;
  int w   = tid >> 6;
  int l   = tid & 63;
  int lg  = l >> 4;
  int lc  = l & 15;

  const unsigned short* xrow = xT + ((size_t)b * N_ + n0 + w * 16 + lc) * C_;
  const unsigned short* wrow0 = wbf + (size_t)(o0 + lc) * C_;

  const f32x4 zc = {0.f, 0.f, 0.f, 0.f};
  f32x4 acc[4] = {zc, zc, zc, zc};

  for (int k0 = 0; k0 < C_; k0 += 32) {
    bf16x8 bfrag = *(const bf16x8*)(xrow + k0 + lg * 8);
#pragma unroll
    for (int sub = 0; sub < 4; sub++) {
      bf16x8 afrag = *(const bf16x8*)(wrow0 + (size_t)sub * 16 * C_ + k0 + lg * 8);
      acc[sub] = __builtin_amdgcn_mfma_f32_16x16x32_bf16(afrag, bfrag, acc[sub], 0, 0, 0);
    }
  }

  const float* bias_t = (t == 0) ? bq : (t == 1) ? bk : bv;
  int n = n0 + w * 16 + lc;

#pragma unroll
  for (int sub = 0; sub < 4; sub++) {
    int oobase = (o0 & 127) + sub * 16;
    float4 bs = *(const float4*)(bias_t + oobase + lg * 4);
    float val[4];
    val[0] = acc[sub][0] + bs.x;
    val[1] = acc[sub][1] + bs.y;
    val[2] = acc[sub][2] + bs.z;
    val[3] = acc[sub][3] + bs.w;
    int h  = oobase >> 5;
    int d0 = (oobase & 31) + lg * 4;
    if (t < 2) {
      unsigned short* dst = (t == 0 ? qws : kws)
                          + (((size_t)(b * NH + h)) * N_ + n) * DH_ + d0;
      alignas(8) unsigned short tmp[4];
#pragma unroll
      for (int r = 0; r < 4; r++) tmp[r] = f2bf(val[r]);
      *(uint2*)dst = *(const uint2*)tmp;
    } else {
      unsigned short* dst = vtws + (((size_t)(b * NH + h)) * DH_ + d0) * N_ + n;
#pragma unroll
      for (int r = 0; r < 4; r++) dst[(size_t)r * N_] = f2bf(val[r]);
    }
  }
}

// ---------------------------------------------------------------------------
// Kernel 2a: Z-pass. Partial sum of 2^s per m-slice -> zparts[ms] (no atomics).
// grid = B * 256 qt * 4 ms = 2048 blocks, 256 threads
// ---------------------------------------------------------------------------
__global__ __launch_bounds__(256)
void z_pass(const unsigned short* __restrict__ qws,
            const unsigned short* __restrict__ kws,
            const float* __restrict__ wfuse,
            float* __restrict__ zparts)      // f32 [4 ms][B][4 g][N]
{
  int bid = blockIdx.x;
  int b   = bid >> 10;
  int rem = bid & 1023;
  int qt  = rem >> 2;
  int ms  = rem & 3;
  int n0  = qt << 4;

  int tid = threadIdx.x;
  int wv_ = tid >> 6;
  int l   = tid & 63;
  int lg  = l >> 4;
  int lc  = l & 15;

  const float TEMP = 11.313708498984761f;    // sqrt(128)
  float wm[4][4];
#pragma unroll
  for (int g = 0; g < 4; g++)
#pragma unroll
    for (int h = 0; h < 4; h++)
      wm[g][h] = wfuse[g * 4 + h] * (LOG2E / TEMP);

  bf16x8 qf[4];
#pragma unroll
  for (int h = 0; h < 4; h++)
    qf[h] = *(const bf16x8*)(qws + (((size_t)(b * NH + h)) * N_ + n0 + lc) * DH_ + lg * 8);

  const f32x4 zc = {0.f, 0.f, 0.f, 0.f};
  float zp[4][4] = {};

  int base = ms << 5;                        // 32 pp per slice
  for (int pp = base + wv_; pp < base + 32; pp += 4) {
#pragma unroll
    for (int mm = 0; mm < 2; mm++) {
      int m0 = pp * 32 + mm * 16;
      f32x4 sh[4];
#pragma unroll
      for (int h = 0; h < 4; h++) {
        bf16x8 kf = *(const bf16x8*)(kws + (((size_t)(b * NH + h)) * N_ + m0 + lc) * DH_ + lg * 8);
        sh[h] = __builtin_amdgcn_mfma_f32_16x16x32_bf16(qf[h], kf, zc, 0, 0, 0);
      }
#pragma unroll
      for (int g = 0; g < 4; g++) {
        f32x4 sg = wm[g][0] * sh[0] + wm[g][1] * sh[1]
                 + wm[g][2] * sh[2] + wm[g][3] * sh[3];
#pragma unroll
        for (int r = 0; r < 4; r++) zp[g][r] += EXP2(sg[r]);
      }
    }
  }

  __shared__ float zred[4][4][4][16];
#pragma unroll
  for (int g = 0; g < 4; g++)
#pragma unroll
    for (int r = 0; r < 4; r++) {
      float v = zp[g][r];
      v += __shfl_xor(v, 1, 16);
      v += __shfl_xor(v, 2, 16);
      v += __shfl_xor(v, 4, 16);
      v += __shfl_xor(v, 8, 16);
      zp[g][r] = v;
    }
  if (lc == 0) {
#pragma unroll
    for (int g = 0; g < 4; g++)
#pragma unroll
      for (int r = 0; r < 4; r++) zred[wv_][g][lg][r] = zp[g][r];
  }
  __syncthreads();
  if (tid < 64) {
    int g   = tid >> 4;
    int row = tid & 15;
    float s = zred[0][g][row >> 2][row & 3] + zred[1][g][row >> 2][row & 3]
            + zred[2][g][row >> 2][row & 3] + zred[3][g][row >> 2][row & 3];
    zparts[(((size_t)ms * B_ + b) * NH + g) * N_ + n0 + row] = s;
  }
}

// ---------------------------------------------------------------------------
// Kernel 2b: P-pass. Identical to round 9 EXCEPT: attn stores are PLAIN
// (ack at L2, background writeback) instead of nontemporal (ack at HBM).
// Single-variable A/B on the nt flag.
// grid = B * 256 = 512 blocks, 512 threads (8 waves split m)
// ---------------------------------------------------------------------------
__global__ __launch_bounds__(512)
void p_pv(const unsigned short* __restrict__ qws,
          const unsigned short* __restrict__ kws,
          const unsigned short* __restrict__ vtws,
          const float* __restrict__ wfuse,
          const float* __restrict__ zparts,  // f32 [4][B][4][N]
          float* __restrict__ attn_out,
          float* __restrict__ pre)           // f32 [B][128][N]
{
  int bid = blockIdx.x;
  int b  = bid >> 8;
  int qt = bid & 255;
  int n0 = qt << 4;

  int tid = threadIdx.x;
  int wv_ = tid >> 6;               // 0..7
  int l   = tid & 63;
  int lg  = l >> 4;
  int lc  = l & 15;

  __shared__ __align__(16) unsigned char lds_raw[8 * 4 * 16 * 40 * 2]; // 40960 B
  unsigned short (*pbuf)[4][16][40] = (unsigned short (*)[4][16][40])lds_raw;
  float (*ored)[16][36] = (float (*)[16][36])lds_raw;

  const float TEMP = 11.313708498984761f;
  float wm[4][4];
#pragma unroll
  for (int g = 0; g < 4; g++)
#pragma unroll
    for (int h = 0; h < 4; h++)
      wm[g][h] = sbc(wfuse[g * 4 + h] * (LOG2E / TEMP));   // SGPR, wave-uniform

  bf16x8 qf[4];
#pragma unroll
  for (int h = 0; h < 4; h++)
    qf[h] = *(const bf16x8*)(qws + (((size_t)(b * NH + h)) * N_ + n0 + lc) * DH_ + lg * 8);

  const size_t ZS = (size_t)B_ * NH * N_;    // slice stride
  float invZ[4][4];
#pragma unroll
  for (int g = 0; g < 4; g++)
#pragma unroll
    for (int r = 0; r < 4; r++) {
      size_t idx = ((size_t)(b * NH + g)) * N_ + n0 + lg * 4 + r;
      float z = zparts[idx] + zparts[ZS + idx] + zparts[2 * ZS + idx] + zparts[3 * ZS + idx];
      invZ[g][r] = 1.0f / z;
    }

  const f32x4 zc = {0.f, 0.f, 0.f, 0.f};
  f32x4 opv[4][2];
#pragma unroll
  for (int g = 0; g < 4; g++) { opv[g][0] = zc; opv[g][1] = zc; }

  float* attn_b = attn_out + (size_t)b * NH * N_ * N_;

  // prime the pipeline: K and V fragments for the first iteration
  bf16x8 kf[2][4];
  bf16x8 vf[4][2];
  {
    int m0p = wv_ * 32;
#pragma unroll
    for (int mm = 0; mm < 2; mm++)
#pragma unroll
      for (int h = 0; h < 4; h++)
        kf[mm][h] = *(const bf16x8*)(kws
            + (((size_t)(b * NH + h)) * N_ + m0p + mm * 16 + lc) * DH_ + lg * 8);
#pragma unroll
    for (int g = 0; g < 4; g++)
#pragma unroll
      for (int dh = 0; dh < 2; dh++)
        vf[g][dh] = *(const bf16x8*)(vtws
            + (((size_t)(b * NH + g)) * DH_ + dh * 16 + lc) * N_ + m0p + lg * 8);
  }

#pragma unroll 1
  for (int pp = wv_; pp < 128; pp += 8) {
    int m0p = pp * 32;
    int ppn = pp + 8;
    int m0n = (ppn < 128 ? ppn : pp) * 32;   // tail: harmless reload

    // ---- 1. prefetch NEXT iteration's K and V fragments (before stores) ----
    bf16x8 kn[2][4];
#pragma unroll
    for (int mm = 0; mm < 2; mm++)
#pragma unroll
      for (int h = 0; h < 4; h++)
        kn[mm][h] = *(const bf16x8*)(kws
            + (((size_t)(b * NH + h)) * N_ + m0n + mm * 16 + lc) * DH_ + lg * 8);
    bf16x8 vn[4][2];
#pragma unroll
    for (int g = 0; g < 4; g++)
#pragma unroll
      for (int dh = 0; dh < 2; dh++)
        vn[g][dh] = *(const bf16x8*)(vtws
            + (((size_t)(b * NH + g)) * DH_ + dh * 16 + lc) * N_ + m0n + lg * 8);

    // ---- 2. scores + head-fuse + exp -> pbuf (kf resident) ----
#pragma unroll
    for (int mm = 0; mm < 2; mm++) {
      f32x4 sh[4];
#pragma unroll
      for (int h = 0; h < 4; h++)
        sh[h] = __builtin_amdgcn_mfma_f32_16x16x32_bf16(qf[h], kf[mm][h], zc, 0, 0, 0);
#pragma unroll
      for (int g = 0; g < 4; g++) {
        f32x4 sg = wm[g][0] * sh[0] + wm[g][1] * sh[1]
                 + wm[g][2] * sh[2] + wm[g][3] * sh[3];
#pragma unroll
        for (int r = 0; r < 4; r++) {
          float p = EXP2(sg[r]) * invZ[g][r];
          pbuf[wv_][g][lg * 4 + r][mm * 16 + lc] = f2bf(p);
        }
      }
    }

    // ---- 3. PV accumulate (vf resident from last sweep's prefetch) ----
#pragma unroll
    for (int g = 0; g < 4; g++) {
      bf16x8 pa = *(const bf16x8*)(&pbuf[wv_][g][lc][lg * 8]);
#pragma unroll
      for (int dh = 0; dh < 2; dh++)
        opv[g][dh] = __builtin_amdgcn_mfma_f32_16x16x32_bf16(pa, vf[g][dh], opv[g][dh], 0, 0, 0);
    }

    // ---- 4. attn stores LAST: bf16->f32 from pbuf, PLAIN float4 stores ----
#pragma unroll
    for (int it = 0; it < 8; it++) {
      int flat = it * 64 + l;
      int g   = flat >> 7;
      int row = (flat >> 3) & 15;
      int seg = flat & 7;
      uint2 pk = *(const uint2*)(&pbuf[wv_][g][row][seg * 4]);
      f32x4 o4;
      o4[0] = __uint_as_float(pk.x << 16);
      o4[1] = __uint_as_float(pk.x & 0xffff0000u);
      o4[2] = __uint_as_float(pk.y << 16);
      o4[3] = __uint_as_float(pk.y & 0xffff0000u);
      *(f32x4*)(attn_b + ((size_t)g * N_ + n0 + row) * N_ + m0p + seg * 4) = o4;
    }

    // ---- 5. rotate pipeline ----
#pragma unroll
    for (int mm = 0; mm < 2; mm++)
#pragma unroll
      for (int h = 0; h < 4; h++)
        kf[mm][h] = kn[mm][h];
#pragma unroll
    for (int g = 0; g < 4; g++)
#pragma unroll
      for (int dh = 0; dh < 2; dh++)
        vf[g][dh] = vn[g][dh];
  }

  __syncthreads();   // all waves done with pbuf; reuse as ored

  int row2 = tid & 15;
  int d2   = tid >> 4;              // 0..31
#pragma unroll
  for (int g = 0; g < 4; g++) {
#pragma unroll
    for (int dh = 0; dh < 2; dh++)
#pragma unroll
      for (int r = 0; r < 4; r++)
        ored[wv_][lg * 4 + r][dh * 16 + lc] = opv[g][dh][r];
    __syncthreads();
    float s = 0.f;
#pragma unroll
    for (int w = 0; w < 8; w++) s += ored[w][row2][d2];
    pre[((size_t)b * HID + g * 32 + d2) * N_ + n0 + row2] = s;
    __syncthreads();
  }
}

// ---------------------------------------------------------------------------
// Kernel 3: out projection (128 -> 512) + BatchNorm (eval). 512 threads.
// ---------------------------------------------------------------------------
__global__ __launch_bounds__(512)
void outproj_bn(const float* __restrict__ pre,
                const float* __restrict__ wout, const float* __restrict__ bout,
                const float* __restrict__ gamma, const float* __restrict__ beta,
                const float* __restrict__ mean,  const float* __restrict__ var,
                float* __restrict__ out)
{
  int bid = blockIdx.x;
  int cot = bid & 3;
  int rem = bid >> 2;
  int b   = rem >> 6;
  int n0  = (rem & 63) << 6;
  int co0 = cot << 7;

  int tid = threadIdx.x;
  int nn = tid & 63;
  int og = tid >> 6;               // 0..7, 16 outputs each

  __shared__ float ps[128][64];

  const float* pb = pre + (size_t)b * HID * N_ + n0;
#pragma unroll
  for (int j = 0; j < 16; j++)
    ps[og * 16 + j][nn] = pb[(size_t)(og * 16 + j) * N_ + nn];
  __syncthreads();

  float acc[16];
#pragma unroll
  for (int j = 0; j < 16; j++) acc[j] = bout[co0 + og * 16 + j];

  for (int k0 = 0; k0 < HID; k0 += 16) {
    float xv[16];
#pragma unroll
    for (int cc = 0; cc < 16; cc++) xv[cc] = ps[k0 + cc][nn];

    const float* wbase = wout + (size_t)(co0 + og * 16) * HID + k0;
#pragma unroll
    for (int j = 0; j < 16; j++) {
      const float* wr = wbase + (size_t)j * HID;
#pragma unroll
      for (int q4 = 0; q4 < 4; q4++) {
        float4 w4 = *(const float4*)(wr + q4 * 4);
        acc[j] = fmaf(w4.x, xv[q4 * 4 + 0], acc[j]);
        acc[j] = fmaf(w4.y, xv[q4 * 4 + 1], acc[j]);
        acc[j] = fmaf(w4.z, xv[q4 * 4 + 2], acc[j]);
        acc[j] = fmaf(w4.w, xv[q4 * 4 + 3], acc[j]);
      }
    }
  }

#pragma unroll
  for (int j = 0; j < 16; j++) {
    int co = co0 + og * 16 + j;
    float sc = gamma[co] * rsqrtf(var[co] + 1e-5f);
    float v  = (acc[j] - mean[co]) * sc + beta[co];
    out[((size_t)b * C_ + co) * N_ + n0 + nn] = v;
  }
}

// ---------------------------------------------------------------------------
extern "C" void kernel_launch(void* const* d_in, const int* in_sizes, int n_in,
                              void* d_out, int out_size, void* d_ws, size_t ws_size,
                              hipStream_t stream)
{
  const float* x     = (const float*)d_in[0];
  const float* wq    = (const float*)d_in[1];
  const float* bq    = (const float*)d_in[2];
  const float* wk    = (const float*)d_in[3];
  const float* bk    = (const float*)d_in[4];
  const float* wv    = (const float*)d_in[5];
  const float* bv    = (const float*)d_in[6];
  const float* wfuse = (const float*)d_in[7];
  const float* wout  = (const float*)d_in[8];
  const float* bout  = (const float*)d_in[9];
  const float* gamma = (const float*)d_in[10];
  const float* beta  = (const float*)d_in[11];
  const float* mean  = (const float*)d_in[12];
  const float* var   = (const float*)d_in[13];

  // ws layout (bytes):
  //   [0, 2M)        q  bf16 [2][4][4096][32]
  //   [2M, 4M)       k  bf16 [2][4][4096][32]
  //   [4M, 6M)       vT bf16 [2][4][32][4096]
  //   [6M, 14M)      xT bf16 [2][4096][512]   (dead after qkv_gemm)
  //   [6M, 10M)      pre f32 [2][128][4096]   (overlaps xT; live from p_pv on)
  //   [10M, 10.5M)   zparts f32 [4][2][4][4096] (overlaps dead xT tail)
  //   [14M, ~14.4M)  wbf bf16 [384][512]
  const size_t QK_ELEMS = (size_t)B_ * NH * N_ * DH_;   // 1,048,576
  char* base = (char*)d_ws;
  unsigned short* qws  = (unsigned short*)base;
  unsigned short* kws  = qws + QK_ELEMS;
  unsigned short* vtws = kws + QK_ELEMS;
  unsigned short* xT   = (unsigned short*)(base + 3 * QK_ELEMS * sizeof(unsigned short));
  float* pre           = (float*)(base + 3 * QK_ELEMS * sizeof(unsigned short));
  float* zparts        = (float*)(base + 3 * QK_ELEMS * sizeof(unsigned short)
                                  + (size_t)4 * 1024 * 1024);
  unsigned short* wbf  = (unsigned short*)(base + 3 * QK_ELEMS * sizeof(unsigned short)
                                           + (size_t)B_ * N_ * C_ * sizeof(unsigned short));

  float* out_f  = (float*)d_out;                         // [2][512][4096]
  float* attn_f = out_f + (size_t)B_ * C_ * N_;          // [2][4][4096][4096]

  hipLaunchKernelGGL(prep_w,   dim3(192),  dim3(256), 0, stream, wq, wk, wv, wbf);
  hipLaunchKernelGGL(prep_xt,  dim3(1024), dim3(256), 0, stream, x, xT);
  hipLaunchKernelGGL(qkv_gemm, dim3(768),  dim3(256), 0, stream,
                     wbf, xT, bq, bk, bv, qws, kws, vtws);
  hipLaunchKernelGGL(z_pass, dim3(2048), dim3(256), 0, stream,
                     qws, kws, wfuse, zparts);
  hipLaunchKernelGGL(p_pv, dim3(512), dim3(512), 0, stream,
                     qws, kws, vtws, wfuse, zparts, attn_f, pre);
  hipLaunchKernelGGL(outproj_bn, dim3(512), dim3(512), 0, stream,
                     pre, wout, bout, gamma, beta, mean, var, out_f);
}

// Round 11
// 298.836 us; speedup vs baseline: 1.1424x; 1.1424x over previous
//
#include <hip/hip_runtime.h>
#include <hip/hip_bf16.h>
#include <cstdint>
#include <cstddef>

#define B_   2
#define C_   512
#define N_   4096
#define NH   4
#define DH_  32
#define HID  128
#define LOG2E 1.4426950408889634f

typedef __attribute__((ext_vector_type(8))) short bf16x8;
typedef __attribute__((ext_vector_type(4))) float f32x4;

#if __has_builtin(__builtin_amdgcn_exp2f)
#define EXP2(x) __builtin_amdgcn_exp2f(x)
#else
#define EXP2(x) exp2f(x)
#endif

static __device__ __forceinline__ unsigned short f2bf(float f) {
  union { float f; unsigned int u; } v; v.f = f;
  unsigned int r = v.u + 0x7fffu + ((v.u >> 16) & 1u);
  return (unsigned short)(r >> 16);
}

static __device__ __forceinline__ float sbc(float x) {  // force to SGPR
  return __uint_as_float(__builtin_amdgcn_readfirstlane(__float_as_uint(x)));
}

// ---------------------------------------------------------------------------
// Prep A: convert wq|wk|wv (f32 [128][512] each) -> wbf bf16 [384][512]
// ---------------------------------------------------------------------------
__global__ __launch_bounds__(256)
void prep_w(const float* __restrict__ wq, const float* __restrict__ wk,
            const float* __restrict__ wv, unsigned short* __restrict__ wbf)
{
  int gid  = blockIdx.x * 256 + threadIdx.x;
  int elem = gid * 4;
  int t    = elem >> 16;                 // 65536 elems per tensor
  int off  = elem & 65535;
  const float* src = (t == 0) ? wq : (t == 1) ? wk : wv;
  float4 v = *(const float4*)(src + off);
  alignas(8) unsigned short tmp[4];
  tmp[0] = f2bf(v.x); tmp[1] = f2bf(v.y); tmp[2] = f2bf(v.z); tmp[3] = f2bf(v.w);
  *(uint2*)(wbf + t * 65536 + off) = *(const uint2*)tmp;
}

// ---------------------------------------------------------------------------
// Prep B: transpose-convert x f32 [b][c][n] -> xT bf16 [b][n][c]
// ---------------------------------------------------------------------------
__global__ __launch_bounds__(256)
void prep_xt(const float* __restrict__ x, unsigned short* __restrict__ xT)
{
  int bid = blockIdx.x;
  int b   = bid >> 9;
  int rem = bid & 511;
  int ct  = rem >> 6;
  int nt  = rem & 63;
  int c0  = ct << 6;
  int n0  = nt << 6;

  int tid = threadIdx.x;
  __shared__ float xs[64][65];

  const float* xb = x + (size_t)b * C_ * N_;
#pragma unroll
  for (int rr = 0; rr < 16; rr++) {
    int row = (tid >> 6) * 16 + rr;
    xs[row][tid & 63] = xb[(size_t)(c0 + row) * N_ + n0 + (tid & 63)];
  }
  __syncthreads();

  int cseg = (tid & 7) * 8;
#pragma unroll
  for (int pass = 0; pass < 2; pass++) {
    int nrow = pass * 32 + (tid >> 3);
    alignas(16) unsigned short tmp[8];
#pragma unroll
    for (int j = 0; j < 8; j++) tmp[j] = f2bf(xs[cseg + j][nrow]);
    *(uint4*)(xT + ((size_t)b * N_ + n0 + nrow) * C_ + c0 + cseg) = *(const uint4*)tmp;
  }
}

// ---------------------------------------------------------------------------
// Kernel 1: QKV projection as MFMA GEMM. M=384, N=8192, K=512.
// ---------------------------------------------------------------------------
__global__ __launch_bounds__(256)
void qkv_gemm(const unsigned short* __restrict__ wbf,
              const unsigned short* __restrict__ xT,
              const float* __restrict__ bq, const float* __restrict__ bk,
              const float* __restrict__ bv,
              unsigned short* __restrict__ qws,
              unsigned short* __restrict__ kws,
              unsigned short* __restrict__ vtws)
{
  int bid = blockIdx.x;
  int ot  = bid % 6;
  int ntl = bid / 6;                 // 0..127
  int b   = ntl >> 6;
  int n0  = (ntl & 63) << 6;
  int o0  = ot << 6;                 // 0..320
  int t   = o0 >> 7;                 // tensor 0=q 1=k 2=v

  int tid = threadIdx.x;
  int w   = tid >> 6;
  int l   = tid & 63;
  int lg  = l >> 4;
  int lc  = l & 15;

  const unsigned short* xrow = xT + ((size_t)b * N_ + n0 + w * 16 + lc) * C_;
  const unsigned short* wrow0 = wbf + (size_t)(o0 + lc) * C_;

  const f32x4 zc = {0.f, 0.f, 0.f, 0.f};
  f32x4 acc[4] = {zc, zc, zc, zc};

  for (int k0 = 0; k0 < C_; k0 += 32) {
    bf16x8 bfrag = *(const bf16x8*)(xrow + k0 + lg * 8);
#pragma unroll
    for (int sub = 0; sub < 4; sub++) {
      bf16x8 afrag = *(const bf16x8*)(wrow0 + (size_t)sub * 16 * C_ + k0 + lg * 8);
      acc[sub] = __builtin_amdgcn_mfma_f32_16x16x32_bf16(afrag, bfrag, acc[sub], 0, 0, 0);
    }
  }

  const float* bias_t = (t == 0) ? bq : (t == 1) ? bk : bv;
  int n = n0 + w * 16 + lc;

#pragma unroll
  for (int sub = 0; sub < 4; sub++) {
    int oobase = (o0 & 127) + sub * 16;
    float4 bs = *(const float4*)(bias_t + oobase + lg * 4);
    float val[4];
    val[0] = acc[sub][0] + bs.x;
    val[1] = acc[sub][1] + bs.y;
    val[2] = acc[sub][2] + bs.z;
    val[3] = acc[sub][3] + bs.w;
    int h  = oobase >> 5;
    int d0 = (oobase & 31) + lg * 4;
    if (t < 2) {
      unsigned short* dst = (t == 0 ? qws : kws)
                          + (((size_t)(b * NH + h)) * N_ + n) * DH_ + d0;
      alignas(8) unsigned short tmp[4];
#pragma unroll
      for (int r = 0; r < 4; r++) tmp[r] = f2bf(val[r]);
      *(uint2*)dst = *(const uint2*)tmp;
    } else {
      unsigned short* dst = vtws + (((size_t)(b * NH + h)) * DH_ + d0) * N_ + n;
#pragma unroll
      for (int r = 0; r < 4; r++) dst[(size_t)r * N_] = f2bf(val[r]);
    }
  }
}

// ---------------------------------------------------------------------------
// Kernel 2: fused Z-sweep + P-sweep attention.
// Z-sweep: each of 8 waves accumulates sum(2^s) over its m-subset (no stores),
// cross-wave reduce via shfl + zred LDS -> invZ in-register.
// P-sweep: round-7 structure — K prefetched 1 iter ahead, pbuf LDS, windowed V,
// nontemporal attn stores LAST (proven best: R10 A/B nt vs plain = -36 us).
// grid = B * 256 = 512 blocks, 512 threads
// ---------------------------------------------------------------------------
__global__ __launch_bounds__(512)
void attn_zpv(const unsigned short* __restrict__ qws,
              const unsigned short* __restrict__ kws,
              const unsigned short* __restrict__ vtws,
              const float* __restrict__ wfuse,
              float* __restrict__ attn_out,
              float* __restrict__ pre)       // f32 [B][128][N]
{
  int bid = blockIdx.x;
  int b  = bid >> 8;
  int qt = bid & 255;
  int n0 = qt << 4;

  int tid = threadIdx.x;
  int wv_ = tid >> 6;               // 0..7
  int l   = tid & 63;
  int lg  = l >> 4;
  int lc  = l & 15;

  __shared__ __align__(16) unsigned char lds_raw[8 * 4 * 16 * 40 * 2]; // 40960 B
  unsigned short (*pbuf)[4][16][40] = (unsigned short (*)[4][16][40])lds_raw;
  float (*ored)[16][36] = (float (*)[16][36])lds_raw;
  __shared__ float zred[8][4][4][4];   // [wave][g][lg][r]

  const float TEMP = 11.313708498984761f;
  float wm[4][4];
#pragma unroll
  for (int g = 0; g < 4; g++)
#pragma unroll
    for (int h = 0; h < 4; h++)
      wm[g][h] = sbc(wfuse[g * 4 + h] * (LOG2E / TEMP));   // SGPR, wave-uniform

  bf16x8 qf[4];
#pragma unroll
  for (int h = 0; h < 4; h++)
    qf[h] = *(const bf16x8*)(qws + (((size_t)(b * NH + h)) * N_ + n0 + lc) * DH_ + lg * 8);

  const f32x4 zc = {0.f, 0.f, 0.f, 0.f};

  // ================= Z-sweep =================
  float zp[4][4] = {};
#pragma unroll 1
  for (int pp = wv_; pp < 128; pp += 8) {
#pragma unroll
    for (int mm = 0; mm < 2; mm++) {
      int m0 = pp * 32 + mm * 16;
      f32x4 sh[4];
#pragma unroll
      for (int h = 0; h < 4; h++) {
        bf16x8 kf = *(const bf16x8*)(kws
            + (((size_t)(b * NH + h)) * N_ + m0 + lc) * DH_ + lg * 8);
        sh[h] = __builtin_amdgcn_mfma_f32_16x16x32_bf16(qf[h], kf, zc, 0, 0, 0);
      }
#pragma unroll
      for (int g = 0; g < 4; g++) {
        f32x4 sg = wm[g][0] * sh[0] + wm[g][1] * sh[1]
                 + wm[g][2] * sh[2] + wm[g][3] * sh[3];
#pragma unroll
        for (int r = 0; r < 4; r++) zp[g][r] += EXP2(sg[r]);
      }
    }
  }

#pragma unroll
  for (int g = 0; g < 4; g++)
#pragma unroll
    for (int r = 0; r < 4; r++) {
      float v = zp[g][r];
      v += __shfl_xor(v, 1, 16);
      v += __shfl_xor(v, 2, 16);
      v += __shfl_xor(v, 4, 16);
      v += __shfl_xor(v, 8, 16);
      zp[g][r] = v;
    }
  if (lc == 0) {
#pragma unroll
    for (int g = 0; g < 4; g++)
#pragma unroll
      for (int r = 0; r < 4; r++) zred[wv_][g][lg][r] = zp[g][r];
  }
  __syncthreads();

  float invZ[4][4];
#pragma unroll
  for (int g = 0; g < 4; g++)
#pragma unroll
    for (int r = 0; r < 4; r++) {
      float z = 0.f;
#pragma unroll
      for (int w = 0; w < 8; w++) z += zred[w][g][lg][r];
      invZ[g][r] = 1.0f / z;
    }

  // ================= P-sweep (R7 structure) =================
  f32x4 opv[4][2];
#pragma unroll
  for (int g = 0; g < 4; g++) { opv[g][0] = zc; opv[g][1] = zc; }

  float* attn_b = attn_out + (size_t)b * NH * N_ * N_;

  // prime the pipeline: K fragments for the first iteration
  bf16x8 kf[2][4];
  {
    int m0p = wv_ * 32;
#pragma unroll
    for (int mm = 0; mm < 2; mm++)
#pragma unroll
      for (int h = 0; h < 4; h++)
        kf[mm][h] = *(const bf16x8*)(kws
            + (((size_t)(b * NH + h)) * N_ + m0p + mm * 16 + lc) * DH_ + lg * 8);
  }

#pragma unroll 1
  for (int pp = wv_; pp < 128; pp += 8) {
    int m0p = pp * 32;
    int ppn = pp + 8;
    int m0n = (ppn < 128 ? ppn : pp) * 32;   // tail: harmless reload

    // ---- 1. prefetch NEXT iteration's K fragments (before any store) ----
    bf16x8 kn[2][4];
#pragma unroll
    for (int mm = 0; mm < 2; mm++)
#pragma unroll
      for (int h = 0; h < 4; h++)
        kn[mm][h] = *(const bf16x8*)(kws
            + (((size_t)(b * NH + h)) * N_ + m0n + mm * 16 + lc) * DH_ + lg * 8);

    // ---- 2. scores + head-fuse + exp -> pbuf (kf resident; no vmem wait) ----
#pragma unroll
    for (int mm = 0; mm < 2; mm++) {
      f32x4 sh[4];
#pragma unroll
      for (int h = 0; h < 4; h++)
        sh[h] = __builtin_amdgcn_mfma_f32_16x16x32_bf16(qf[h], kf[mm][h], zc, 0, 0, 0);
#pragma unroll
      for (int g = 0; g < 4; g++) {
        f32x4 sg = wm[g][0] * sh[0] + wm[g][1] * sh[1]
                 + wm[g][2] * sh[2] + wm[g][3] * sh[3];
#pragma unroll
        for (int r = 0; r < 4; r++) {
          float p = EXP2(sg[r]) * invZ[g][r];
          pbuf[wv_][g][lg * 4 + r][mm * 16 + lc] = f2bf(p);
        }
      }
    }

    // ---- 3. PV accumulate, V fragments windowed ----
#pragma unroll
    for (int g = 0; g < 4; g++) {
      bf16x8 pa = *(const bf16x8*)(&pbuf[wv_][g][lc][lg * 8]);
#pragma unroll
      for (int dh = 0; dh < 2; dh++) {
        bf16x8 vb = *(const bf16x8*)(vtws
            + (((size_t)(b * NH + g)) * DH_ + dh * 16 + lc) * N_ + m0p + lg * 8);
        opv[g][dh] = __builtin_amdgcn_mfma_f32_16x16x32_bf16(pa, vb, opv[g][dh], 0, 0, 0);
      }
    }

    // ---- 4. attn stores LAST: bf16->f32 from pbuf, float4 nontemporal ----
#pragma unroll
    for (int it = 0; it < 8; it++) {
      int flat = it * 64 + l;
      int g   = flat >> 7;
      int row = (flat >> 3) & 15;
      int seg = flat & 7;
      uint2 pk = *(const uint2*)(&pbuf[wv_][g][row][seg * 4]);
      f32x4 o4;
      o4[0] = __uint_as_float(pk.x << 16);
      o4[1] = __uint_as_float(pk.x & 0xffff0000u);
      o4[2] = __uint_as_float(pk.y << 16);
      o4[3] = __uint_as_float(pk.y & 0xffff0000u);
      __builtin_nontemporal_store(o4,
          (f32x4*)(attn_b + ((size_t)g * N_ + n0 + row) * N_ + m0p + seg * 4));
    }

    // ---- 5. rotate pipeline ----
#pragma unroll
    for (int mm = 0; mm < 2; mm++)
#pragma unroll
      for (int h = 0; h < 4; h++)
        kf[mm][h] = kn[mm][h];
  }

  __syncthreads();   // all waves done with pbuf; reuse as ored

  int row2 = tid & 15;
  int d2   = tid >> 4;              // 0..31
#pragma unroll
  for (int g = 0; g < 4; g++) {
#pragma unroll
    for (int dh = 0; dh < 2; dh++)
#pragma unroll
      for (int r = 0; r < 4; r++)
        ored[wv_][lg * 4 + r][dh * 16 + lc] = opv[g][dh][r];
    __syncthreads();
    float s = 0.f;
#pragma unroll
    for (int w = 0; w < 8; w++) s += ored[w][row2][d2];
    pre[((size_t)b * HID + g * 32 + d2) * N_ + n0 + row2] = s;
    __syncthreads();
  }
}

// ---------------------------------------------------------------------------
// Kernel 3: out projection (128 -> 512) + BatchNorm (eval). 512 threads.
// ---------------------------------------------------------------------------
__global__ __launch_bounds__(512)
void outproj_bn(const float* __restrict__ pre,
                const float* __restrict__ wout, const float* __restrict__ bout,
                const float* __restrict__ gamma, const float* __restrict__ beta,
                const float* __restrict__ mean,  const float* __restrict__ var,
                float* __restrict__ out)
{
  int bid = blockIdx.x;
  int cot = bid & 3;
  int rem = bid >> 2;
  int b   = rem >> 6;
  int n0  = (rem & 63) << 6;
  int co0 = cot << 7;

  int tid = threadIdx.x;
  int nn = tid & 63;
  int og = tid >> 6;               // 0..7, 16 outputs each

  __shared__ float ps[128][64];

  const float* pb = pre + (size_t)b * HID * N_ + n0;
#pragma unroll
  for (int j = 0; j < 16; j++)
    ps[og * 16 + j][nn] = pb[(size_t)(og * 16 + j) * N_ + nn];
  __syncthreads();

  float acc[16];
#pragma unroll
  for (int j = 0; j < 16; j++) acc[j] = bout[co0 + og * 16 + j];

  for (int k0 = 0; k0 < HID; k0 += 16) {
    float xv[16];
#pragma unroll
    for (int cc = 0; cc < 16; cc++) xv[cc] = ps[k0 + cc][nn];

    const float* wbase = wout + (size_t)(co0 + og * 16) * HID + k0;
#pragma unroll
    for (int j = 0; j < 16; j++) {
      const float* wr = wbase + (size_t)j * HID;
#pragma unroll
      for (int q4 = 0; q4 < 4; q4++) {
        float4 w4 = *(const float4*)(wr + q4 * 4);
        acc[j] = fmaf(w4.x, xv[q4 * 4 + 0], acc[j]);
        acc[j] = fmaf(w4.y, xv[q4 * 4 + 1], acc[j]);
        acc[j] = fmaf(w4.z, xv[q4 * 4 + 2], acc[j]);
        acc[j] = fmaf(w4.w, xv[q4 * 4 + 3], acc[j]);
      }
    }
  }

#pragma unroll
  for (int j = 0; j < 16; j++) {
    int co = co0 + og * 16 + j;
    float sc = gamma[co] * rsqrtf(var[co] + 1e-5f);
    float v  = (acc[j] - mean[co]) * sc + beta[co];
    out[((size_t)b * C_ + co) * N_ + n0 + nn] = v;
  }
}

// ---------------------------------------------------------------------------
extern "C" void kernel_launch(void* const* d_in, const int* in_sizes, int n_in,
                              void* d_out, int out_size, void* d_ws, size_t ws_size,
                              hipStream_t stream)
{
  const float* x     = (const float*)d_in[0];
  const float* wq    = (const float*)d_in[1];
  const float* bq    = (const float*)d_in[2];
  const float* wk    = (const float*)d_in[3];
  const float* bk    = (const float*)d_in[4];
  const float* wv    = (const float*)d_in[5];
  const float* bv    = (const float*)d_in[6];
  const float* wfuse = (const float*)d_in[7];
  const float* wout  = (const float*)d_in[8];
  const float* bout  = (const float*)d_in[9];
  const float* gamma = (const float*)d_in[10];
  const float* beta  = (const float*)d_in[11];
  const float* mean  = (const float*)d_in[12];
  const float* var   = (const float*)d_in[13];

  // ws layout (bytes):
  //   [0, 2M)        q  bf16 [2][4][4096][32]
  //   [2M, 4M)       k  bf16 [2][4][4096][32]
  //   [4M, 6M)       vT bf16 [2][4][32][4096]
  //   [6M, 14M)      xT bf16 [2][4096][512]   (dead after qkv_gemm)
  //   [6M, 10M)      pre f32 [2][128][4096]   (overlaps xT; live from attn_zpv on)
  //   [14M, ~14.4M)  wbf bf16 [384][512]
  const size_t QK_ELEMS = (size_t)B_ * NH * N_ * DH_;   // 1,048,576
  char* base = (char*)d_ws;
  unsigned short* qws  = (unsigned short*)base;
  unsigned short* kws  = qws + QK_ELEMS;
  unsigned short* vtws = kws + QK_ELEMS;
  unsigned short* xT   = (unsigned short*)(base + 3 * QK_ELEMS * sizeof(unsigned short));
  float* pre           = (float*)(base + 3 * QK_ELEMS * sizeof(unsigned short));
  unsigned short* wbf  = (unsigned short*)(base + 3 * QK_ELEMS * sizeof(unsigned short)
                                           + (size_t)B_ * N_ * C_ * sizeof(unsigned short));

  float* out_f  = (float*)d_out;                         // [2][512][4096]
  float* attn_f = out_f + (size_t)B_ * C_ * N_;          // [2][4][4096][4096]

  hipLaunchKernelGGL(prep_w,   dim3(192),  dim3(256), 0, stream, wq, wk, wv, wbf);
  hipLaunchKernelGGL(prep_xt,  dim3(1024), dim3(256), 0, stream, x, xT);
  hipLaunchKernelGGL(qkv_gemm, dim3(768),  dim3(256), 0, stream,
                     wbf, xT, bq, bk, bv, qws, kws, vtws);
  hipLaunchKernelGGL(attn_zpv, dim3(512), dim3(512), 0, stream,
                     qws, kws, vtws, wfuse, attn_f, pre);
  hipLaunchKernelGGL(outproj_bn, dim3(512), dim3(512), 0, stream,
                     pre, wout, bout, gamma, beta, mean, var, out_f);
}

// Round 12
// 282.792 us; speedup vs baseline: 1.2072x; 1.0567x over previous
//
#include <hip/hip_runtime.h>
#include <hip/hip_bf16.h>
#include <cstdint>
#include <cstddef>

#define B_   2
#define C_   512
#define N_   4096
#define NH   4
#define DH_  32
#define HID  128
#define LOG2E 1.4426950408889634f

typedef __attribute__((ext_vector_type(8))) short bf16x8;
typedef __attribute__((ext_vector_type(4))) float f32x4;

#if __has_builtin(__builtin_amdgcn_exp2f)
#define EXP2(x) __builtin_amdgcn_exp2f(x)
#else
#define EXP2(x) exp2f(x)
#endif

static __device__ __forceinline__ unsigned short f2bf(float f) {
  union { float f; unsigned int u; } v; v.f = f;
  unsigned int r = v.u + 0x7fffu + ((v.u >> 16) & 1u);
  return (unsigned short)(r >> 16);
}

static __device__ __forceinline__ float sbc(float x) {  // force to SGPR
  return __uint_as_float(__builtin_amdgcn_readfirstlane(__float_as_uint(x)));
}

// ---------------------------------------------------------------------------
// Prep A: convert wq|wk|wv (f32 [128][512] each) -> wbf bf16 [384][512]
// ---------------------------------------------------------------------------
__global__ __launch_bounds__(256)
void prep_w(const float* __restrict__ wq, const float* __restrict__ wk,
            const float* __restrict__ wv, unsigned short* __restrict__ wbf)
{
  int gid  = blockIdx.x * 256 + threadIdx.x;
  int elem = gid * 4;
  int t    = elem >> 16;                 // 65536 elems per tensor
  int off  = elem & 65535;
  const float* src = (t == 0) ? wq : (t == 1) ? wk : wv;
  float4 v = *(const float4*)(src + off);
  alignas(8) unsigned short tmp[4];
  tmp[0] = f2bf(v.x); tmp[1] = f2bf(v.y); tmp[2] = f2bf(v.z); tmp[3] = f2bf(v.w);
  *(uint2*)(wbf + t * 65536 + off) = *(const uint2*)tmp;
}

// ---------------------------------------------------------------------------
// Prep B: transpose-convert x f32 [b][c][n] -> xT bf16 [b][n][c]
// ---------------------------------------------------------------------------
__global__ __launch_bounds__(256)
void prep_xt(const float* __restrict__ x, unsigned short* __restrict__ xT)
{
  int bid = blockIdx.x;
  int b   = bid >> 9;
  int rem = bid & 511;
  int ct  = rem >> 6;
  int nt  = rem & 63;
  int c0  = ct << 6;
  int n0  = nt << 6;

  int tid = threadIdx.x;
  __shared__ float xs[64][65];

  const float* xb = x + (size_t)b * C_ * N_;
#pragma unroll
  for (int rr = 0; rr < 16; rr++) {
    int row = (tid >> 6) * 16 + rr;
    xs[row][tid & 63] = xb[(size_t)(c0 + row) * N_ + n0 + (tid & 63)];
  }
  __syncthreads();

  int cseg = (tid & 7) * 8;
#pragma unroll
  for (int pass = 0; pass < 2; pass++) {
    int nrow = pass * 32 + (tid >> 3);
    alignas(16) unsigned short tmp[8];
#pragma unroll
    for (int j = 0; j < 8; j++) tmp[j] = f2bf(xs[cseg + j][nrow]);
    *(uint4*)(xT + ((size_t)b * N_ + n0 + nrow) * C_ + c0 + cseg) = *(const uint4*)tmp;
  }
}

// ---------------------------------------------------------------------------
// Kernel 1: QKV projection as MFMA GEMM. M=384, N=8192, K=512.
// ---------------------------------------------------------------------------
__global__ __launch_bounds__(256)
void qkv_gemm(const unsigned short* __restrict__ wbf,
              const unsigned short* __restrict__ xT,
              const float* __restrict__ bq, const float* __restrict__ bk,
              const float* __restrict__ bv,
              unsigned short* __restrict__ qws,
              unsigned short* __restrict__ kws,
              unsigned short* __restrict__ vtws)
{
  int bid = blockIdx.x;
  int ot  = bid % 6;
  int ntl = bid / 6;                 // 0..127
  int b   = ntl >> 6;
  int n0  = (ntl & 63) << 6;
  int o0  = ot << 6;                 // 0..320
  int t   = o0 >> 7;                 // tensor 0=q 1=k 2=v

  int tid = threadIdx.x;
  int w   = tid >> 6;
  int l   = tid & 63;
  int lg  = l >> 4;
  int lc  = l & 15;

  const unsigned short* xrow = xT + ((size_t)b * N_ + n0 + w * 16 + lc) * C_;
  const unsigned short* wrow0 = wbf + (size_t)(o0 + lc) * C_;

  const f32x4 zc = {0.f, 0.f, 0.f, 0.f};
  f32x4 acc[4] = {zc, zc, zc, zc};

  for (int k0 = 0; k0 < C_; k0 += 32) {
    bf16x8 bfrag = *(const bf16x8*)(xrow + k0 + lg * 8);
#pragma unroll
    for (int sub = 0; sub < 4; sub++) {
      bf16x8 afrag = *(const bf16x8*)(wrow0 + (size_t)sub * 16 * C_ + k0 + lg * 8);
      acc[sub] = __builtin_amdgcn_mfma_f32_16x16x32_bf16(afrag, bfrag, acc[sub], 0, 0, 0);
    }
  }

  const float* bias_t = (t == 0) ? bq : (t == 1) ? bk : bv;
  int n = n0 + w * 16 + lc;

#pragma unroll
  for (int sub = 0; sub < 4; sub++) {
    int oobase = (o0 & 127) + sub * 16;
    float4 bs = *(const float4*)(bias_t + oobase + lg * 4);
    float val[4];
    val[0] = acc[sub][0] + bs.x;
    val[1] = acc[sub][1] + bs.y;
    val[2] = acc[sub][2] + bs.z;
    val[3] = acc[sub][3] + bs.w;
    int h  = oobase >> 5;
    int d0 = (oobase & 31) + lg * 4;
    if (t < 2) {
      unsigned short* dst = (t == 0 ? qws : kws)
                          + (((size_t)(b * NH + h)) * N_ + n) * DH_ + d0;
      alignas(8) unsigned short tmp[4];
#pragma unroll
      for (int r = 0; r < 4; r++) tmp[r] = f2bf(val[r]);
      *(uint2*)dst = *(const uint2*)tmp;
    } else {
      unsigned short* dst = vtws + (((size_t)(b * NH + h)) * DH_ + d0) * N_ + n;
#pragma unroll
      for (int r = 0; r < 4; r++) dst[(size_t)r * N_] = f2bf(val[r]);
    }
  }
}

// ---------------------------------------------------------------------------
// Kernel 2: fused Z-sweep + P-sweep attention, XCD-partitioned.
// Block decode maps XCDs 0-3 -> b=0, XCDs 4-7 -> b=1 (dispatch round-robins
// bid%8 across XCDs), so each XCD's L2 holds K+V for ONE batch (2 MB < 4 MB)
// instead of both (6 MB > 4 MB). Z-sweep warms K; P-sweep = R7 structure
// (K prefetch 1 iter ahead, pbuf LDS, windowed V, nt stores last).
// grid = B * 256 = 512 blocks, 512 threads
// ---------------------------------------------------------------------------
__global__ __launch_bounds__(512)
void attn_zpv(const unsigned short* __restrict__ qws,
              const unsigned short* __restrict__ kws,
              const unsigned short* __restrict__ vtws,
              const float* __restrict__ wfuse,
              float* __restrict__ attn_out,
              float* __restrict__ pre)       // f32 [B][128][N]
{
  int bid = blockIdx.x;
  int xcd = bid & 7;                // dispatch: bid%8 -> XCD
  int b   = xcd >> 2;               // XCD 0-3: b=0, XCD 4-7: b=1
  int qt  = (bid >> 3) * 4 + (xcd & 3);   // bijective over [0,256)
  int n0  = qt << 4;

  int tid = threadIdx.x;
  int wv_ = tid >> 6;               // 0..7
  int l   = tid & 63;
  int lg  = l >> 4;
  int lc  = l & 15;

  __shared__ __align__(16) unsigned char lds_raw[8 * 4 * 16 * 40 * 2]; // 40960 B
  unsigned short (*pbuf)[4][16][40] = (unsigned short (*)[4][16][40])lds_raw;
  float (*ored)[16][36] = (float (*)[16][36])lds_raw;
  __shared__ float zred[8][4][4][4];   // [wave][g][lg][r]

  const float TEMP = 11.313708498984761f;
  float wm[4][4];
#pragma unroll
  for (int g = 0; g < 4; g++)
#pragma unroll
    for (int h = 0; h < 4; h++)
      wm[g][h] = sbc(wfuse[g * 4 + h] * (LOG2E / TEMP));   // SGPR, wave-uniform

  bf16x8 qf[4];
#pragma unroll
  for (int h = 0; h < 4; h++)
    qf[h] = *(const bf16x8*)(qws + (((size_t)(b * NH + h)) * N_ + n0 + lc) * DH_ + lg * 8);

  const f32x4 zc = {0.f, 0.f, 0.f, 0.f};

  // ================= Z-sweep =================
  float zp[4][4] = {};
#pragma unroll 1
  for (int pp = wv_; pp < 128; pp += 8) {
#pragma unroll
    for (int mm = 0; mm < 2; mm++) {
      int m0 = pp * 32 + mm * 16;
      f32x4 sh[4];
#pragma unroll
      for (int h = 0; h < 4; h++) {
        bf16x8 kf = *(const bf16x8*)(kws
            + (((size_t)(b * NH + h)) * N_ + m0 + lc) * DH_ + lg * 8);
        sh[h] = __builtin_amdgcn_mfma_f32_16x16x32_bf16(qf[h], kf, zc, 0, 0, 0);
      }
#pragma unroll
      for (int g = 0; g < 4; g++) {
        f32x4 sg = wm[g][0] * sh[0] + wm[g][1] * sh[1]
                 + wm[g][2] * sh[2] + wm[g][3] * sh[3];
#pragma unroll
        for (int r = 0; r < 4; r++) zp[g][r] += EXP2(sg[r]);
      }
    }
  }

#pragma unroll
  for (int g = 0; g < 4; g++)
#pragma unroll
    for (int r = 0; r < 4; r++) {
      float v = zp[g][r];
      v += __shfl_xor(v, 1, 16);
      v += __shfl_xor(v, 2, 16);
      v += __shfl_xor(v, 4, 16);
      v += __shfl_xor(v, 8, 16);
      zp[g][r] = v;
    }
  if (lc == 0) {
#pragma unroll
    for (int g = 0; g < 4; g++)
#pragma unroll
      for (int r = 0; r < 4; r++) zred[wv_][g][lg][r] = zp[g][r];
  }
  __syncthreads();

  float invZ[4][4];
#pragma unroll
  for (int g = 0; g < 4; g++)
#pragma unroll
    for (int r = 0; r < 4; r++) {
      float z = 0.f;
#pragma unroll
      for (int w = 0; w < 8; w++) z += zred[w][g][lg][r];
      invZ[g][r] = 1.0f / z;
    }

  // ================= P-sweep (R7 structure) =================
  f32x4 opv[4][2];
#pragma unroll
  for (int g = 0; g < 4; g++) { opv[g][0] = zc; opv[g][1] = zc; }

  float* attn_b = attn_out + (size_t)b * NH * N_ * N_;

  // prime the pipeline: K fragments for the first iteration
  bf16x8 kf[2][4];
  {
    int m0p = wv_ * 32;
#pragma unroll
    for (int mm = 0; mm < 2; mm++)
#pragma unroll
      for (int h = 0; h < 4; h++)
        kf[mm][h] = *(const bf16x8*)(kws
            + (((size_t)(b * NH + h)) * N_ + m0p + mm * 16 + lc) * DH_ + lg * 8);
  }

#pragma unroll 1
  for (int pp = wv_; pp < 128; pp += 8) {
    int m0p = pp * 32;
    int ppn = pp + 8;
    int m0n = (ppn < 128 ? ppn : pp) * 32;   // tail: harmless reload

    // ---- 1. prefetch NEXT iteration's K fragments (before any store) ----
    bf16x8 kn[2][4];
#pragma unroll
    for (int mm = 0; mm < 2; mm++)
#pragma unroll
      for (int h = 0; h < 4; h++)
        kn[mm][h] = *(const bf16x8*)(kws
            + (((size_t)(b * NH + h)) * N_ + m0n + mm * 16 + lc) * DH_ + lg * 8);

    // ---- 2. scores + head-fuse + exp -> pbuf (kf resident; no vmem wait) ----
#pragma unroll
    for (int mm = 0; mm < 2; mm++) {
      f32x4 sh[4];
#pragma unroll
      for (int h = 0; h < 4; h++)
        sh[h] = __builtin_amdgcn_mfma_f32_16x16x32_bf16(qf[h], kf[mm][h], zc, 0, 0, 0);
#pragma unroll
      for (int g = 0; g < 4; g++) {
        f32x4 sg = wm[g][0] * sh[0] + wm[g][1] * sh[1]
                 + wm[g][2] * sh[2] + wm[g][3] * sh[3];
#pragma unroll
        for (int r = 0; r < 4; r++) {
          float p = EXP2(sg[r]) * invZ[g][r];
          pbuf[wv_][g][lg * 4 + r][mm * 16 + lc] = f2bf(p);
        }
      }
    }

    // ---- 3. PV accumulate, V fragments windowed ----
#pragma unroll
    for (int g = 0; g < 4; g++) {
      bf16x8 pa = *(const bf16x8*)(&pbuf[wv_][g][lc][lg * 8]);
#pragma unroll
      for (int dh = 0; dh < 2; dh++) {
        bf16x8 vb = *(const bf16x8*)(vtws
            + (((size_t)(b * NH + g)) * DH_ + dh * 16 + lc) * N_ + m0p + lg * 8);
        opv[g][dh] = __builtin_amdgcn_mfma_f32_16x16x32_bf16(pa, vb, opv[g][dh], 0, 0, 0);
      }
    }

    // ---- 4. attn stores LAST: bf16->f32 from pbuf, float4 nontemporal ----
#pragma unroll
    for (int it = 0; it < 8; it++) {
      int flat = it * 64 + l;
      int g   = flat >> 7;
      int row = (flat >> 3) & 15;
      int seg = flat & 7;
      uint2 pk = *(const uint2*)(&pbuf[wv_][g][row][seg * 4]);
      f32x4 o4;
      o4[0] = __uint_as_float(pk.x << 16);
      o4[1] = __uint_as_float(pk.x & 0xffff0000u);
      o4[2] = __uint_as_float(pk.y << 16);
      o4[3] = __uint_as_float(pk.y & 0xffff0000u);
      __builtin_nontemporal_store(o4,
          (f32x4*)(attn_b + ((size_t)g * N_ + n0 + row) * N_ + m0p + seg * 4));
    }

    // ---- 5. rotate pipeline ----
#pragma unroll
    for (int mm = 0; mm < 2; mm++)
#pragma unroll
      for (int h = 0; h < 4; h++)
        kf[mm][h] = kn[mm][h];
  }

  __syncthreads();   // all waves done with pbuf; reuse as ored

  int row2 = tid & 15;
  int d2   = tid >> 4;              // 0..31
#pragma unroll
  for (int g = 0; g < 4; g++) {
#pragma unroll
    for (int dh = 0; dh < 2; dh++)
#pragma unroll
      for (int r = 0; r < 4; r++)
        ored[wv_][lg * 4 + r][dh * 16 + lc] = opv[g][dh][r];
    __syncthreads();
    float s = 0.f;
#pragma unroll
    for (int w = 0; w < 8; w++) s += ored[w][row2][d2];
    pre[((size_t)b * HID + g * 32 + d2) * N_ + n0 + row2] = s;
    __syncthreads();
  }
}

// ---------------------------------------------------------------------------
// Kernel 3: out projection (128 -> 512) + BatchNorm (eval). 512 threads.
// ---------------------------------------------------------------------------
__global__ __launch_bounds__(512)
void outproj_bn(const float* __restrict__ pre,
                const float* __restrict__ wout, const float* __restrict__ bout,
                const float* __restrict__ gamma, const float* __restrict__ beta,
                const float* __restrict__ mean,  const float* __restrict__ var,
                float* __restrict__ out)
{
  int bid = blockIdx.x;
  int cot = bid & 3;
  int rem = bid >> 2;
  int b   = rem >> 6;
  int n0  = (rem & 63) << 6;
  int co0 = cot << 7;

  int tid = threadIdx.x;
  int nn = tid & 63;
  int og = tid >> 6;               // 0..7, 16 outputs each

  __shared__ float ps[128][64];

  const float* pb = pre + (size_t)b * HID * N_ + n0;
#pragma unroll
  for (int j = 0; j < 16; j++)
    ps[og * 16 + j][nn] = pb[(size_t)(og * 16 + j) * N_ + nn];
  __syncthreads();

  float acc[16];
#pragma unroll
  for (int j = 0; j < 16; j++) acc[j] = bout[co0 + og * 16 + j];

  for (int k0 = 0; k0 < HID; k0 += 16) {
    float xv[16];
#pragma unroll
    for (int cc = 0; cc < 16; cc++) xv[cc] = ps[k0 + cc][nn];

    const float* wbase = wout + (size_t)(co0 + og * 16) * HID + k0;
#pragma unroll
    for (int j = 0; j < 16; j++) {
      const float* wr = wbase + (size_t)j * HID;
#pragma unroll
      for (int q4 = 0; q4 < 4; q4++) {
        float4 w4 = *(const float4*)(wr + q4 * 4);
        acc[j] = fmaf(w4.x, xv[q4 * 4 + 0], acc[j]);
        acc[j] = fmaf(w4.y, xv[q4 * 4 + 1], acc[j]);
        acc[j] = fmaf(w4.z, xv[q4 * 4 + 2], acc[j]);
        acc[j] = fmaf(w4.w, xv[q4 * 4 + 3], acc[j]);
      }
    }
  }

#pragma unroll
  for (int j = 0; j < 16; j++) {
    int co = co0 + og * 16 + j;
    float sc = gamma[co] * rsqrtf(var[co] + 1e-5f);
    float v  = (acc[j] - mean[co]) * sc + beta[co];
    out[((size_t)b * C_ + co) * N_ + n0 + nn] = v;
  }
}

// ---------------------------------------------------------------------------
extern "C" void kernel_launch(void* const* d_in, const int* in_sizes, int n_in,
                              void* d_out, int out_size, void* d_ws, size_t ws_size,
                              hipStream_t stream)
{
  const float* x     = (const float*)d_in[0];
  const float* wq    = (const float*)d_in[1];
  const float* bq    = (const float*)d_in[2];
  const float* wk    = (const float*)d_in[3];
  const float* bk    = (const float*)d_in[4];
  const float* wv    = (const float*)d_in[5];
  const float* bv    = (const float*)d_in[6];
  const float* wfuse = (const float*)d_in[7];
  const float* wout  = (const float*)d_in[8];
  const float* bout  = (const float*)d_in[9];
  const float* gamma = (const float*)d_in[10];
  const float* beta  = (const float*)d_in[11];
  const float* mean  = (const float*)d_in[12];
  const float* var   = (const float*)d_in[13];

  // ws layout (bytes):
  //   [0, 2M)        q  bf16 [2][4][4096][32]
  //   [2M, 4M)       k  bf16 [2][4][4096][32]
  //   [4M, 6M)       vT bf16 [2][4][32][4096]
  //   [6M, 14M)      xT bf16 [2][4096][512]   (dead after qkv_gemm)
  //   [6M, 10M)      pre f32 [2][128][4096]   (overlaps xT; live from attn_zpv on)
  //   [14M, ~14.4M)  wbf bf16 [384][512]
  const size_t QK_ELEMS = (size_t)B_ * NH * N_ * DH_;   // 1,048,576
  char* base = (char*)d_ws;
  unsigned short* qws  = (unsigned short*)base;
  unsigned short* kws  = qws + QK_ELEMS;
  unsigned short* vtws = kws + QK_ELEMS;
  unsigned short* xT   = (unsigned short*)(base + 3 * QK_ELEMS * sizeof(unsigned short));
  float* pre           = (float*)(base + 3 * QK_ELEMS * sizeof(unsigned short));
  unsigned short* wbf  = (unsigned short*)(base + 3 * QK_ELEMS * sizeof(unsigned short)
                                           + (size_t)B_ * N_ * C_ * sizeof(unsigned short));

  float* out_f  = (float*)d_out;                         // [2][512][4096]
  float* attn_f = out_f + (size_t)B_ * C_ * N_;          // [2][4][4096][4096]

  hipLaunchKernelGGL(prep_w,   dim3(192),  dim3(256), 0, stream, wq, wk, wv, wbf);
  hipLaunchKernelGGL(prep_xt,  dim3(1024), dim3(256), 0, stream, x, xT);
  hipLaunchKernelGGL(qkv_gemm, dim3(768),  dim3(256), 0, stream,
                     wbf, xT, bq, bk, bv, qws, kws, vtws);
  hipLaunchKernelGGL(attn_zpv, dim3(512), dim3(512), 0, stream,
                     qws, kws, vtws, wfuse, attn_f, pre);
  hipLaunchKernelGGL(outproj_bn, dim3(512), dim3(512), 0, stream,
                     pre, wout, bout, gamma, beta, mean, var, out_f);
}

// Round 13
// 228.146 us; speedup vs baseline: 1.4964x; 1.2395x over previous
//
#include <hip/hip_runtime.h>
#include <hip/hip_bf16.h>
#include <cstdint>
#include <cstddef>

#define B_   2
#define C_   512
#define N_   4096
#define NH   4
#define DH_  32
#define HID  128
#define LOG2E 1.4426950408889634f

typedef __attribute__((ext_vector_type(8))) short bf16x8;
typedef __attribute__((ext_vector_type(4))) float f32x4;

#if __has_builtin(__builtin_amdgcn_exp2f)
#define EXP2(x) __builtin_amdgcn_exp2f(x)
#else
#define EXP2(x) exp2f(x)
#endif

static __device__ __forceinline__ unsigned short f2bf(float f) {
  union { float f; unsigned int u; } v; v.f = f;
  unsigned int r = v.u + 0x7fffu + ((v.u >> 16) & 1u);
  return (unsigned short)(r >> 16);
}

static __device__ __forceinline__ float sbc(float x) {  // force to SGPR
  return __uint_as_float(__builtin_amdgcn_readfirstlane(__float_as_uint(x)));
}

// ---------------------------------------------------------------------------
// Prep A: convert wq|wk|wv|wout -> bf16 wbf [384][512] + woutbf [512][128];
// block 256 computes BN fold: gs = gamma*rsqrt(var+eps), shift=(b-mu)*gs+beta
// grid = 257 x 256 thr
// ---------------------------------------------------------------------------
__global__ __launch_bounds__(256)
void prep_w(const float* __restrict__ wq, const float* __restrict__ wk,
            const float* __restrict__ wv, const float* __restrict__ wout,
            const float* __restrict__ bout, const float* __restrict__ gamma,
            const float* __restrict__ beta, const float* __restrict__ mean,
            const float* __restrict__ var,
            unsigned short* __restrict__ wbf,   // [4*65536] shorts
            float* __restrict__ gsws, float* __restrict__ shws)
{
  if (blockIdx.x == 256) {
    int co = threadIdx.x;
#pragma unroll
    for (int i = 0; i < 2; i++, co += 256) {
      float gs = gamma[co] * rsqrtf(var[co] + 1e-5f);
      gsws[co] = gs;
      shws[co] = (bout[co] - mean[co]) * gs + beta[co];
    }
    return;
  }
  int gid  = blockIdx.x * 256 + threadIdx.x;
  int elem = gid * 4;
  int t    = elem >> 16;                 // 65536 elems per tensor
  int off  = elem & 65535;
  const float* src = (t == 0) ? wq : (t == 1) ? wk : (t == 2) ? wv : wout;
  float4 v = *(const float4*)(src + off);
  alignas(8) unsigned short tmp[4];
  tmp[0] = f2bf(v.x); tmp[1] = f2bf(v.y); tmp[2] = f2bf(v.z); tmp[3] = f2bf(v.w);
  *(uint2*)(wbf + t * 65536 + off) = *(const uint2*)tmp;
}

// ---------------------------------------------------------------------------
// Prep B: transpose-convert x f32 [b][c][n] -> xT bf16 [b][n][c]
// ---------------------------------------------------------------------------
__global__ __launch_bounds__(256)
void prep_xt(const float* __restrict__ x, unsigned short* __restrict__ xT)
{
  int bid = blockIdx.x;
  int b   = bid >> 9;
  int rem = bid & 511;
  int ct  = rem >> 6;
  int nt  = rem & 63;
  int c0  = ct << 6;
  int n0  = nt << 6;

  int tid = threadIdx.x;
  __shared__ float xs[64][65];

  const float* xb = x + (size_t)b * C_ * N_;
#pragma unroll
  for (int rr = 0; rr < 16; rr++) {
    int row = (tid >> 6) * 16 + rr;
    xs[row][tid & 63] = xb[(size_t)(c0 + row) * N_ + n0 + (tid & 63)];
  }
  __syncthreads();

  int cseg = (tid & 7) * 8;
#pragma unroll
  for (int pass = 0; pass < 2; pass++) {
    int nrow = pass * 32 + (tid >> 3);
    alignas(16) unsigned short tmp[8];
#pragma unroll
    for (int j = 0; j < 8; j++) tmp[j] = f2bf(xs[cseg + j][nrow]);
    *(uint4*)(xT + ((size_t)b * N_ + n0 + nrow) * C_ + c0 + cseg) = *(const uint4*)tmp;
  }
}

// ---------------------------------------------------------------------------
// Kernel 1: QKV projection as MFMA GEMM. M=384, N=8192, K=512.
// ---------------------------------------------------------------------------
__global__ __launch_bounds__(256)
void qkv_gemm(const unsigned short* __restrict__ wbf,
              const unsigned short* __restrict__ xT,
              const float* __restrict__ bq, const float* __restrict__ bk,
              const float* __restrict__ bv,
              unsigned short* __restrict__ qws,
              unsigned short* __restrict__ kws,
              unsigned short* __restrict__ vtws)
{
  int bid = blockIdx.x;
  int ot  = bid % 6;
  int ntl = bid / 6;                 // 0..127
  int b   = ntl >> 6;
  int n0  = (ntl & 63) << 6;
  int o0  = ot << 6;                 // 0..320
  int t   = o0 >> 7;                 // tensor 0=q 1=k 2=v

  int tid = threadIdx.x;
  int w   = tid >> 6;
  int l   = tid & 63;
  int lg  = l >> 4;
  int lc  = l & 15;

  const unsigned short* xrow = xT + ((size_t)b * N_ + n0 + w * 16 + lc) * C_;
  const unsigned short* wrow0 = wbf + (size_t)(o0 + lc) * C_;

  const f32x4 zc = {0.f, 0.f, 0.f, 0.f};
  f32x4 acc[4] = {zc, zc, zc, zc};

  for (int k0 = 0; k0 < C_; k0 += 32) {
    bf16x8 bfrag = *(const bf16x8*)(xrow + k0 + lg * 8);
#pragma unroll
    for (int sub = 0; sub < 4; sub++) {
      bf16x8 afrag = *(const bf16x8*)(wrow0 + (size_t)sub * 16 * C_ + k0 + lg * 8);
      acc[sub] = __builtin_amdgcn_mfma_f32_16x16x32_bf16(afrag, bfrag, acc[sub], 0, 0, 0);
    }
  }

  const float* bias_t = (t == 0) ? bq : (t == 1) ? bk : bv;
  int n = n0 + w * 16 + lc;

#pragma unroll
  for (int sub = 0; sub < 4; sub++) {
    int oobase = (o0 & 127) + sub * 16;
    float4 bs = *(const float4*)(bias_t + oobase + lg * 4);
    float val[4];
    val[0] = acc[sub][0] + bs.x;
    val[1] = acc[sub][1] + bs.y;
    val[2] = acc[sub][2] + bs.z;
    val[3] = acc[sub][3] + bs.w;
    int h  = oobase >> 5;
    int d0 = (oobase & 31) + lg * 4;
    if (t < 2) {
      unsigned short* dst = (t == 0 ? qws : kws)
                          + (((size_t)(b * NH + h)) * N_ + n) * DH_ + d0;
      alignas(8) unsigned short tmp[4];
#pragma unroll
      for (int r = 0; r < 4; r++) tmp[r] = f2bf(val[r]);
      *(uint2*)dst = *(const uint2*)tmp;
    } else {
      unsigned short* dst = vtws + (((size_t)(b * NH + h)) * DH_ + d0) * N_ + n;
#pragma unroll
      for (int r = 0; r < 4; r++) dst[(size_t)r * N_] = f2bf(val[r]);
    }
  }
}

// ---------------------------------------------------------------------------
// Kernel 2: fused Z-sweep + P-sweep attention + out-projection + BN.
// XCD-partitioned block decode (R12). Z-sweep -> invZ in-register. P-sweep =
// R7 structure (K prefetch 1 iter ahead, pbuf LDS, windowed V, nt stores).
// Epilogue: cross-wave PV reduce -> bf16 o128[16][132] -> per-wave 64co x 16n
// MFMA out-GEMM (K=128) with folded BN scale/shift -> out. No pre tensor.
// grid = B * 256 = 512 blocks, 512 threads
// ---------------------------------------------------------------------------
__global__ __launch_bounds__(512)
void attn_zpv(const unsigned short* __restrict__ qws,
              const unsigned short* __restrict__ kws,
              const unsigned short* __restrict__ vtws,
              const float* __restrict__ wfuse,
              const unsigned short* __restrict__ woutbf,  // [512][128] bf16
              const float* __restrict__ gsws, const float* __restrict__ shws,
              float* __restrict__ attn_out,
              float* __restrict__ out)        // [B][512][N]
{
  int bid = blockIdx.x;
  int xcd = bid & 7;                // dispatch: bid%8 -> XCD
  int b   = xcd >> 2;               // XCD 0-3: b=0, XCD 4-7: b=1
  int qt  = (bid >> 3) * 4 + (xcd & 3);   // bijective over [0,256)
  int n0  = qt << 4;

  int tid = threadIdx.x;
  int wv_ = tid >> 6;               // 0..7
  int l   = tid & 63;
  int lg  = l >> 4;
  int lc  = l & 15;

  __shared__ __align__(16) unsigned char lds_raw[8 * 4 * 16 * 40 * 2]; // 40960 B
  unsigned short (*pbuf)[4][16][40] = (unsigned short (*)[4][16][40])lds_raw;
  float (*ored)[16][36] = (float (*)[16][36])lds_raw;                  // 18432 B
  unsigned short (*o128)[132] =
      (unsigned short (*)[132])(lds_raw + 20480);                      // 4224 B
  __shared__ float zred[8][4][4][4];   // [wave][g][lg][r]

  const float TEMP = 11.313708498984761f;
  float wm[4][4];
#pragma unroll
  for (int g = 0; g < 4; g++)
#pragma unroll
    for (int h = 0; h < 4; h++)
      wm[g][h] = sbc(wfuse[g * 4 + h] * (LOG2E / TEMP));   // SGPR, wave-uniform

  bf16x8 qf[4];
#pragma unroll
  for (int h = 0; h < 4; h++)
    qf[h] = *(const bf16x8*)(qws + (((size_t)(b * NH + h)) * N_ + n0 + lc) * DH_ + lg * 8);

  const f32x4 zc = {0.f, 0.f, 0.f, 0.f};

  // ================= Z-sweep =================
  float zp[4][4] = {};
#pragma unroll 1
  for (int pp = wv_; pp < 128; pp += 8) {
#pragma unroll
    for (int mm = 0; mm < 2; mm++) {
      int m0 = pp * 32 + mm * 16;
      f32x4 sh[4];
#pragma unroll
      for (int h = 0; h < 4; h++) {
        bf16x8 kf = *(const bf16x8*)(kws
            + (((size_t)(b * NH + h)) * N_ + m0 + lc) * DH_ + lg * 8);
        sh[h] = __builtin_amdgcn_mfma_f32_16x16x32_bf16(qf[h], kf, zc, 0, 0, 0);
      }
#pragma unroll
      for (int g = 0; g < 4; g++) {
        f32x4 sg = wm[g][0] * sh[0] + wm[g][1] * sh[1]
                 + wm[g][2] * sh[2] + wm[g][3] * sh[3];
#pragma unroll
        for (int r = 0; r < 4; r++) zp[g][r] += EXP2(sg[r]);
      }
    }
  }

#pragma unroll
  for (int g = 0; g < 4; g++)
#pragma unroll
    for (int r = 0; r < 4; r++) {
      float v = zp[g][r];
      v += __shfl_xor(v, 1, 16);
      v += __shfl_xor(v, 2, 16);
      v += __shfl_xor(v, 4, 16);
      v += __shfl_xor(v, 8, 16);
      zp[g][r] = v;
    }
  if (lc == 0) {
#pragma unroll
    for (int g = 0; g < 4; g++)
#pragma unroll
      for (int r = 0; r < 4; r++) zred[wv_][g][lg][r] = zp[g][r];
  }
  __syncthreads();

  float invZ[4][4];
#pragma unroll
  for (int g = 0; g < 4; g++)
#pragma unroll
    for (int r = 0; r < 4; r++) {
      float z = 0.f;
#pragma unroll
      for (int w = 0; w < 8; w++) z += zred[w][g][lg][r];
      invZ[g][r] = 1.0f / z;
    }

  // ================= P-sweep (R7 structure) =================
  f32x4 opv[4][2];
#pragma unroll
  for (int g = 0; g < 4; g++) { opv[g][0] = zc; opv[g][1] = zc; }

  float* attn_b = attn_out + (size_t)b * NH * N_ * N_;

  bf16x8 kf[2][4];
  {
    int m0p = wv_ * 32;
#pragma unroll
    for (int mm = 0; mm < 2; mm++)
#pragma unroll
      for (int h = 0; h < 4; h++)
        kf[mm][h] = *(const bf16x8*)(kws
            + (((size_t)(b * NH + h)) * N_ + m0p + mm * 16 + lc) * DH_ + lg * 8);
  }

#pragma unroll 1
  for (int pp = wv_; pp < 128; pp += 8) {
    int m0p = pp * 32;
    int ppn = pp + 8;
    int m0n = (ppn < 128 ? ppn : pp) * 32;   // tail: harmless reload

    // ---- 1. prefetch NEXT iteration's K fragments (before any store) ----
    bf16x8 kn[2][4];
#pragma unroll
    for (int mm = 0; mm < 2; mm++)
#pragma unroll
      for (int h = 0; h < 4; h++)
        kn[mm][h] = *(const bf16x8*)(kws
            + (((size_t)(b * NH + h)) * N_ + m0n + mm * 16 + lc) * DH_ + lg * 8);

    // ---- 2. scores + head-fuse + exp -> pbuf ----
#pragma unroll
    for (int mm = 0; mm < 2; mm++) {
      f32x4 sh[4];
#pragma unroll
      for (int h = 0; h < 4; h++)
        sh[h] = __builtin_amdgcn_mfma_f32_16x16x32_bf16(qf[h], kf[mm][h], zc, 0, 0, 0);
#pragma unroll
      for (int g = 0; g < 4; g++) {
        f32x4 sg = wm[g][0] * sh[0] + wm[g][1] * sh[1]
                 + wm[g][2] * sh[2] + wm[g][3] * sh[3];
#pragma unroll
        for (int r = 0; r < 4; r++) {
          float p = EXP2(sg[r]) * invZ[g][r];
          pbuf[wv_][g][lg * 4 + r][mm * 16 + lc] = f2bf(p);
        }
      }
    }

    // ---- 3. PV accumulate, V fragments windowed ----
#pragma unroll
    for (int g = 0; g < 4; g++) {
      bf16x8 pa = *(const bf16x8*)(&pbuf[wv_][g][lc][lg * 8]);
#pragma unroll
      for (int dh = 0; dh < 2; dh++) {
        bf16x8 vb = *(const bf16x8*)(vtws
            + (((size_t)(b * NH + g)) * DH_ + dh * 16 + lc) * N_ + m0p + lg * 8);
        opv[g][dh] = __builtin_amdgcn_mfma_f32_16x16x32_bf16(pa, vb, opv[g][dh], 0, 0, 0);
      }
    }

    // ---- 4. attn stores LAST: bf16->f32 from pbuf, float4 nontemporal ----
#pragma unroll
    for (int it = 0; it < 8; it++) {
      int flat = it * 64 + l;
      int g   = flat >> 7;
      int row = (flat >> 3) & 15;
      int seg = flat & 7;
      uint2 pk = *(const uint2*)(&pbuf[wv_][g][row][seg * 4]);
      f32x4 o4;
      o4[0] = __uint_as_float(pk.x << 16);
      o4[1] = __uint_as_float(pk.x & 0xffff0000u);
      o4[2] = __uint_as_float(pk.y << 16);
      o4[3] = __uint_as_float(pk.y & 0xffff0000u);
      __builtin_nontemporal_store(o4,
          (f32x4*)(attn_b + ((size_t)g * N_ + n0 + row) * N_ + m0p + seg * 4));
    }

    // ---- 5. rotate pipeline ----
#pragma unroll
    for (int mm = 0; mm < 2; mm++)
#pragma unroll
      for (int h = 0; h < 4; h++)
        kf[mm][h] = kn[mm][h];
  }

  __syncthreads();   // all waves done with pbuf; reuse as ored

  // ===== cross-wave PV reduce -> bf16 o128[n][o] (o = g*32+d) =====
  int row2 = tid & 15;
  int d2   = tid >> 4;              // 0..31
#pragma unroll
  for (int g = 0; g < 4; g++) {
#pragma unroll
    for (int dh = 0; dh < 2; dh++)
#pragma unroll
      for (int r = 0; r < 4; r++)
        ored[wv_][lg * 4 + r][dh * 16 + lc] = opv[g][dh][r];
    __syncthreads();
    float s = 0.f;
#pragma unroll
    for (int w = 0; w < 8; w++) s += ored[w][row2][d2];
    o128[row2][g * 32 + d2] = f2bf(s);
    __syncthreads();
  }

  // ===== fused out-projection (K=128) + BN =====
  int cb = wv_ * 64;                 // this wave's 64 output channels
  f32x4 oacc[4] = {zc, zc, zc, zc};
#pragma unroll
  for (int kk = 0; kk < 4; kk++) {
    bf16x8 bfrag = *(const bf16x8*)(&o128[lc][kk * 32 + lg * 8]);
#pragma unroll
    for (int sub = 0; sub < 4; sub++) {
      bf16x8 afrag = *(const bf16x8*)(woutbf
          + (size_t)(cb + sub * 16 + lc) * HID + kk * 32 + lg * 8);
      oacc[sub] = __builtin_amdgcn_mfma_f32_16x16x32_bf16(afrag, bfrag, oacc[sub], 0, 0, 0);
    }
  }

  float* outb = out + (size_t)b * C_ * N_;
#pragma unroll
  for (int sub = 0; sub < 4; sub++) {
    int co0 = cb + sub * 16 + lg * 4;
    float4 g4 = *(const float4*)(gsws + co0);
    float4 s4 = *(const float4*)(shws + co0);
    outb[(size_t)(co0 + 0) * N_ + n0 + lc] = oacc[sub][0] * g4.x + s4.x;
    outb[(size_t)(co0 + 1) * N_ + n0 + lc] = oacc[sub][1] * g4.y + s4.y;
    outb[(size_t)(co0 + 2) * N_ + n0 + lc] = oacc[sub][2] * g4.z + s4.z;
    outb[(size_t)(co0 + 3) * N_ + n0 + lc] = oacc[sub][3] * g4.w + s4.w;
  }
}

// ---------------------------------------------------------------------------
extern "C" void kernel_launch(void* const* d_in, const int* in_sizes, int n_in,
                              void* d_out, int out_size, void* d_ws, size_t ws_size,
                              hipStream_t stream)
{
  const float* x     = (const float*)d_in[0];
  const float* wq    = (const float*)d_in[1];
  const float* bq    = (const float*)d_in[2];
  const float* wk    = (const float*)d_in[3];
  const float* bk    = (const float*)d_in[4];
  const float* wv    = (const float*)d_in[5];
  const float* bv    = (const float*)d_in[6];
  const float* wfuse = (const float*)d_in[7];
  const float* wout  = (const float*)d_in[8];
  const float* bout  = (const float*)d_in[9];
  const float* gamma = (const float*)d_in[10];
  const float* beta  = (const float*)d_in[11];
  const float* mean  = (const float*)d_in[12];
  const float* var   = (const float*)d_in[13];

  // ws layout (bytes):
  //   [0, 2M)        q  bf16 [2][4][4096][32]
  //   [2M, 4M)       k  bf16 [2][4][4096][32]
  //   [4M, 6M)       vT bf16 [2][4][32][4096]
  //   [6M, 14M)      xT bf16 [2][4096][512]   (dead after qkv_gemm)
  //   [14M, +512K)   wbf bf16 [384][512] + woutbf [512][128]
  //   then gsws f32[512], shws f32[512]
  const size_t QK_ELEMS = (size_t)B_ * NH * N_ * DH_;   // 1,048,576
  char* base = (char*)d_ws;
  unsigned short* qws  = (unsigned short*)base;
  unsigned short* kws  = qws + QK_ELEMS;
  unsigned short* vtws = kws + QK_ELEMS;
  unsigned short* xT   = (unsigned short*)(base + 3 * QK_ELEMS * sizeof(unsigned short));
  unsigned short* wbf  = (unsigned short*)(base + 3 * QK_ELEMS * sizeof(unsigned short)
                                           + (size_t)B_ * N_ * C_ * sizeof(unsigned short));
  unsigned short* woutbf = wbf + 3 * 65536;
  float* gsws = (float*)(wbf + 4 * 65536);
  float* shws = gsws + C_;

  float* out_f  = (float*)d_out;                         // [2][512][4096]
  float* attn_f = out_f + (size_t)B_ * C_ * N_;          // [2][4][4096][4096]

  hipLaunchKernelGGL(prep_w,   dim3(257),  dim3(256), 0, stream,
                     wq, wk, wv, wout, bout, gamma, beta, mean, var,
                     wbf, gsws, shws);
  hipLaunchKernelGGL(prep_xt,  dim3(1024), dim3(256), 0, stream, x, xT);
  hipLaunchKernelGGL(qkv_gemm, dim3(768),  dim3(256), 0, stream,
                     wbf, xT, bq, bk, bv, qws, kws, vtws);
  hipLaunchKernelGGL(attn_zpv, dim3(512), dim3(512), 0, stream,
                     qws, kws, vtws, wfuse, woutbf, gsws, shws, attn_f, out_f);
}

// Round 14
// 222.987 us; speedup vs baseline: 1.5310x; 1.0231x over previous
//
#include <hip/hip_runtime.h>
#include <hip/hip_bf16.h>
#include <cstdint>
#include <cstddef>

#define B_   2
#define C_   512
#define N_   4096
#define NH   4
#define DH_  32
#define HID  128
#define LOG2E 1.4426950408889634f

typedef __attribute__((ext_vector_type(8))) short bf16x8;
typedef __attribute__((ext_vector_type(4))) float f32x4;

#if __has_builtin(__builtin_amdgcn_exp2f)
#define EXP2(x) __builtin_amdgcn_exp2f(x)
#else
#define EXP2(x) exp2f(x)
#endif

static __device__ __forceinline__ unsigned short f2bf(float f) {
  union { float f; unsigned int u; } v; v.f = f;
  unsigned int r = v.u + 0x7fffu + ((v.u >> 16) & 1u);
  return (unsigned short)(r >> 16);
}

static __device__ __forceinline__ float sbc(float x) {  // force to SGPR
  return __uint_as_float(__builtin_amdgcn_readfirstlane(__float_as_uint(x)));
}

// ---------------------------------------------------------------------------
// Prep A: convert wq|wk|wv|wout -> bf16 wbf [384][512] + woutbf [512][128];
// block 256 computes BN fold: gs = gamma*rsqrt(var+eps), shift=(b-mu)*gs+beta
// grid = 257 x 256 thr
// ---------------------------------------------------------------------------
__global__ __launch_bounds__(256)
void prep_w(const float* __restrict__ wq, const float* __restrict__ wk,
            const float* __restrict__ wv, const float* __restrict__ wout,
            const float* __restrict__ bout, const float* __restrict__ gamma,
            const float* __restrict__ beta, const float* __restrict__ mean,
            const float* __restrict__ var,
            unsigned short* __restrict__ wbf,   // [4*65536] shorts
            float* __restrict__ gsws, float* __restrict__ shws)
{
  if (blockIdx.x == 256) {
    int co = threadIdx.x;
#pragma unroll
    for (int i = 0; i < 2; i++, co += 256) {
      float gs = gamma[co] * rsqrtf(var[co] + 1e-5f);
      gsws[co] = gs;
      shws[co] = (bout[co] - mean[co]) * gs + beta[co];
    }
    return;
  }
  int gid  = blockIdx.x * 256 + threadIdx.x;
  int elem = gid * 4;
  int t    = elem >> 16;                 // 65536 elems per tensor
  int off  = elem & 65535;
  const float* src = (t == 0) ? wq : (t == 1) ? wk : (t == 2) ? wv : wout;
  float4 v = *(const float4*)(src + off);
  alignas(8) unsigned short tmp[4];
  tmp[0] = f2bf(v.x); tmp[1] = f2bf(v.y); tmp[2] = f2bf(v.z); tmp[3] = f2bf(v.w);
  *(uint2*)(wbf + t * 65536 + off) = *(const uint2*)tmp;
}

// ---------------------------------------------------------------------------
// Kernel 1: QKV projection as MFMA GEMM with FUSED x transpose+convert.
// M=384, N=8192, K=512. Per k-step: stage 32c x 64n f32 tile in dbuf LDS
// (reg-staged, loads for step+1 issued right after the barrier), build
// B-frags via LDS reads + f2bf. [32][65] stride -> free 2-way bank alias.
// One barrier per k-step (write buf -> bar -> read buf; dbuf makes the
// write/read of consecutive steps target different buffers).
// grid = 6 o-tiles * 128 n-tiles = 768 blocks, 256 thr
// ---------------------------------------------------------------------------
__global__ __launch_bounds__(256)
void qkv_gemm(const unsigned short* __restrict__ wbf,
              const float* __restrict__ x,
              const float* __restrict__ bq, const float* __restrict__ bk,
              const float* __restrict__ bv,
              unsigned short* __restrict__ qws,
              unsigned short* __restrict__ kws,
              unsigned short* __restrict__ vtws)
{
  int bid = blockIdx.x;
  int ot  = bid % 6;
  int ntl = bid / 6;                 // 0..127
  int b   = ntl >> 6;
  int n0  = (ntl & 63) << 6;
  int o0  = ot << 6;                 // 0..320
  int t   = o0 >> 7;                 // tensor 0=q 1=k 2=v

  int tid = threadIdx.x;
  int w   = tid >> 6;
  int l   = tid & 63;
  int lg  = l >> 4;
  int lc  = l & 15;

  __shared__ float xs[2][32][65];

  int nn    = tid & 63;
  int rbase = tid >> 6;              // 0..3

  const float* xb = x + (size_t)b * C_ * N_ + n0;
  const unsigned short* wrow0 = wbf + (size_t)(o0 + lc) * C_;

  // prologue: load k-rows 0..31 of this n-tile into registers
  float xr[8];
#pragma unroll
  for (int p = 0; p < 8; p++)
    xr[p] = xb[(size_t)(p * 4 + rbase) * N_ + nn];

  const f32x4 zc = {0.f, 0.f, 0.f, 0.f};
  f32x4 acc[4] = {zc, zc, zc, zc};

#pragma unroll 1
  for (int step = 0; step < 16; step++) {
    int buf = step & 1;
    // write staged rows
#pragma unroll
    for (int p = 0; p < 8; p++)
      xs[buf][p * 4 + rbase][nn] = xr[p];
    __syncthreads();
    // issue next tile's loads (latency hidden under MFMA below)
    if (step < 15) {
      int k0n = (step + 1) * 32;
#pragma unroll
      for (int p = 0; p < 8; p++)
        xr[p] = xb[(size_t)(k0n + p * 4 + rbase) * N_ + nn];
    }
    // B-fragment from LDS (+convert), A-fragments from wbf, MFMA
    int k0 = step * 32;
    alignas(16) unsigned short bt[8];
#pragma unroll
    for (int j = 0; j < 8; j++)
      bt[j] = f2bf(xs[buf][lg * 8 + j][w * 16 + lc]);
    bf16x8 bfrag = *(const bf16x8*)bt;
#pragma unroll
    for (int sub = 0; sub < 4; sub++) {
      bf16x8 afrag = *(const bf16x8*)(wrow0 + (size_t)sub * 16 * C_ + k0 + lg * 8);
      acc[sub] = __builtin_amdgcn_mfma_f32_16x16x32_bf16(afrag, bfrag, acc[sub], 0, 0, 0);
    }
  }

  const float* bias_t = (t == 0) ? bq : (t == 1) ? bk : bv;
  int n = n0 + w * 16 + lc;

#pragma unroll
  for (int sub = 0; sub < 4; sub++) {
    int oobase = (o0 & 127) + sub * 16;
    float4 bs = *(const float4*)(bias_t + oobase + lg * 4);
    float val[4];
    val[0] = acc[sub][0] + bs.x;
    val[1] = acc[sub][1] + bs.y;
    val[2] = acc[sub][2] + bs.z;
    val[3] = acc[sub][3] + bs.w;
    int h  = oobase >> 5;
    int d0 = (oobase & 31) + lg * 4;
    if (t < 2) {
      unsigned short* dst = (t == 0 ? qws : kws)
                          + (((size_t)(b * NH + h)) * N_ + n) * DH_ + d0;
      alignas(8) unsigned short tmp[4];
#pragma unroll
      for (int r = 0; r < 4; r++) tmp[r] = f2bf(val[r]);
      *(uint2*)dst = *(const uint2*)tmp;
    } else {
      unsigned short* dst = vtws + (((size_t)(b * NH + h)) * DH_ + d0) * N_ + n;
#pragma unroll
      for (int r = 0; r < 4; r++) dst[(size_t)r * N_] = f2bf(val[r]);
    }
  }
}

// ---------------------------------------------------------------------------
// Kernel 2: fused Z-sweep + P-sweep attention + out-projection + BN.
// XCD-partitioned block decode (R12). Z-sweep -> invZ in-register. P-sweep =
// R7 structure (K prefetch 1 iter ahead, pbuf LDS, windowed V, nt stores).
// Epilogue: cross-wave PV reduce -> bf16 o128[16][132] -> per-wave 64co x 16n
// MFMA out-GEMM (K=128) with folded BN scale/shift -> out.
// grid = B * 256 = 512 blocks, 512 threads
// ---------------------------------------------------------------------------
__global__ __launch_bounds__(512)
void attn_zpv(const unsigned short* __restrict__ qws,
              const unsigned short* __restrict__ kws,
              const unsigned short* __restrict__ vtws,
              const float* __restrict__ wfuse,
              const unsigned short* __restrict__ woutbf,  // [512][128] bf16
              const float* __restrict__ gsws, const float* __restrict__ shws,
              float* __restrict__ attn_out,
              float* __restrict__ out)        // [B][512][N]
{
  int bid = blockIdx.x;
  int xcd = bid & 7;                // dispatch: bid%8 -> XCD
  int b   = xcd >> 2;               // XCD 0-3: b=0, XCD 4-7: b=1
  int qt  = (bid >> 3) * 4 + (xcd & 3);   // bijective over [0,256)
  int n0  = qt << 4;

  int tid = threadIdx.x;
  int wv_ = tid >> 6;               // 0..7
  int l   = tid & 63;
  int lg  = l >> 4;
  int lc  = l & 15;

  __shared__ __align__(16) unsigned char lds_raw[8 * 4 * 16 * 40 * 2]; // 40960 B
  unsigned short (*pbuf)[4][16][40] = (unsigned short (*)[4][16][40])lds_raw;
  float (*ored)[16][36] = (float (*)[16][36])lds_raw;                  // 18432 B
  unsigned short (*o128)[132] =
      (unsigned short (*)[132])(lds_raw + 20480);                      // 4224 B
  __shared__ float zred[8][4][4][4];   // [wave][g][lg][r]

  const float TEMP = 11.313708498984761f;
  float wm[4][4];
#pragma unroll
  for (int g = 0; g < 4; g++)
#pragma unroll
    for (int h = 0; h < 4; h++)
      wm[g][h] = sbc(wfuse[g * 4 + h] * (LOG2E / TEMP));   // SGPR, wave-uniform

  bf16x8 qf[4];
#pragma unroll
  for (int h = 0; h < 4; h++)
    qf[h] = *(const bf16x8*)(qws + (((size_t)(b * NH + h)) * N_ + n0 + lc) * DH_ + lg * 8);

  const f32x4 zc = {0.f, 0.f, 0.f, 0.f};

  // ================= Z-sweep =================
  float zp[4][4] = {};
#pragma unroll 1
  for (int pp = wv_; pp < 128; pp += 8) {
#pragma unroll
    for (int mm = 0; mm < 2; mm++) {
      int m0 = pp * 32 + mm * 16;
      f32x4 sh[4];
#pragma unroll
      for (int h = 0; h < 4; h++) {
        bf16x8 kf = *(const bf16x8*)(kws
            + (((size_t)(b * NH + h)) * N_ + m0 + lc) * DH_ + lg * 8);
        sh[h] = __builtin_amdgcn_mfma_f32_16x16x32_bf16(qf[h], kf, zc, 0, 0, 0);
      }
#pragma unroll
      for (int g = 0; g < 4; g++) {
        f32x4 sg = wm[g][0] * sh[0] + wm[g][1] * sh[1]
                 + wm[g][2] * sh[2] + wm[g][3] * sh[3];
#pragma unroll
        for (int r = 0; r < 4; r++) zp[g][r] += EXP2(sg[r]);
      }
    }
  }

#pragma unroll
  for (int g = 0; g < 4; g++)
#pragma unroll
    for (int r = 0; r < 4; r++) {
      float v = zp[g][r];
      v += __shfl_xor(v, 1, 16);
      v += __shfl_xor(v, 2, 16);
      v += __shfl_xor(v, 4, 16);
      v += __shfl_xor(v, 8, 16);
      zp[g][r] = v;
    }
  if (lc == 0) {
#pragma unroll
    for (int g = 0; g < 4; g++)
#pragma unroll
      for (int r = 0; r < 4; r++) zred[wv_][g][lg][r] = zp[g][r];
  }
  __syncthreads();

  float invZ[4][4];
#pragma unroll
  for (int g = 0; g < 4; g++)
#pragma unroll
    for (int r = 0; r < 4; r++) {
      float z = 0.f;
#pragma unroll
      for (int w = 0; w < 8; w++) z += zred[w][g][lg][r];
      invZ[g][r] = 1.0f / z;
    }

  // ================= P-sweep (R7 structure) =================
  f32x4 opv[4][2];
#pragma unroll
  for (int g = 0; g < 4; g++) { opv[g][0] = zc; opv[g][1] = zc; }

  float* attn_b = attn_out + (size_t)b * NH * N_ * N_;

  bf16x8 kf[2][4];
  {
    int m0p = wv_ * 32;
#pragma unroll
    for (int mm = 0; mm < 2; mm++)
#pragma unroll
      for (int h = 0; h < 4; h++)
        kf[mm][h] = *(const bf16x8*)(kws
            + (((size_t)(b * NH + h)) * N_ + m0p + mm * 16 + lc) * DH_ + lg * 8);
  }

#pragma unroll 1
  for (int pp = wv_; pp < 128; pp += 8) {
    int m0p = pp * 32;
    int ppn = pp + 8;
    int m0n = (ppn < 128 ? ppn : pp) * 32;   // tail: harmless reload

    // ---- 1. prefetch NEXT iteration's K fragments (before any store) ----
    bf16x8 kn[2][4];
#pragma unroll
    for (int mm = 0; mm < 2; mm++)
#pragma unroll
      for (int h = 0; h < 4; h++)
        kn[mm][h] = *(const bf16x8*)(kws
            + (((size_t)(b * NH + h)) * N_ + m0n + mm * 16 + lc) * DH_ + lg * 8);

    // ---- 2. scores + head-fuse + exp -> pbuf ----
#pragma unroll
    for (int mm = 0; mm < 2; mm++) {
      f32x4 sh[4];
#pragma unroll
      for (int h = 0; h < 4; h++)
        sh[h] = __builtin_amdgcn_mfma_f32_16x16x32_bf16(qf[h], kf[mm][h], zc, 0, 0, 0);
#pragma unroll
      for (int g = 0; g < 4; g++) {
        f32x4 sg = wm[g][0] * sh[0] + wm[g][1] * sh[1]
                 + wm[g][2] * sh[2] + wm[g][3] * sh[3];
#pragma unroll
        for (int r = 0; r < 4; r++) {
          float p = EXP2(sg[r]) * invZ[g][r];
          pbuf[wv_][g][lg * 4 + r][mm * 16 + lc] = f2bf(p);
        }
      }
    }

    // ---- 3. PV accumulate, V fragments windowed ----
#pragma unroll
    for (int g = 0; g < 4; g++) {
      bf16x8 pa = *(const bf16x8*)(&pbuf[wv_][g][lc][lg * 8]);
#pragma unroll
      for (int dh = 0; dh < 2; dh++) {
        bf16x8 vb = *(const bf16x8*)(vtws
            + (((size_t)(b * NH + g)) * DH_ + dh * 16 + lc) * N_ + m0p + lg * 8);
        opv[g][dh] = __builtin_amdgcn_mfma_f32_16x16x32_bf16(pa, vb, opv[g][dh], 0, 0, 0);
      }
    }

    // ---- 4. attn stores LAST: bf16->f32 from pbuf, float4 nontemporal ----
#pragma unroll
    for (int it = 0; it < 8; it++) {
      int flat = it * 64 + l;
      int g   = flat >> 7;
      int row = (flat >> 3) & 15;
      int seg = flat & 7;
      uint2 pk = *(const uint2*)(&pbuf[wv_][g][row][seg * 4]);
      f32x4 o4;
      o4[0] = __uint_as_float(pk.x << 16);
      o4[1] = __uint_as_float(pk.x & 0xffff0000u);
      o4[2] = __uint_as_float(pk.y << 16);
      o4[3] = __uint_as_float(pk.y & 0xffff0000u);
      __builtin_nontemporal_store(o4,
          (f32x4*)(attn_b + ((size_t)g * N_ + n0 + row) * N_ + m0p + seg * 4));
    }

    // ---- 5. rotate pipeline ----
#pragma unroll
    for (int mm = 0; mm < 2; mm++)
#pragma unroll
      for (int h = 0; h < 4; h++)
        kf[mm][h] = kn[mm][h];
  }

  __syncthreads();   // all waves done with pbuf; reuse as ored

  // ===== cross-wave PV reduce -> bf16 o128[n][o] (o = g*32+d) =====
  int row2 = tid & 15;
  int d2   = tid >> 4;              // 0..31
#pragma unroll
  for (int g = 0; g < 4; g++) {
#pragma unroll
    for (int dh = 0; dh < 2; dh++)
#pragma unroll
      for (int r = 0; r < 4; r++)
        ored[wv_][lg * 4 + r][dh * 16 + lc] = opv[g][dh][r];
    __syncthreads();
    float s = 0.f;
#pragma unroll
    for (int w = 0; w < 8; w++) s += ored[w][row2][d2];
    o128[row2][g * 32 + d2] = f2bf(s);
    __syncthreads();
  }

  // ===== fused out-projection (K=128) + BN =====
  int cb = wv_ * 64;                 // this wave's 64 output channels
  f32x4 oacc[4] = {zc, zc, zc, zc};
#pragma unroll
  for (int kk = 0; kk < 4; kk++) {
    bf16x8 bfrag = *(const bf16x8*)(&o128[lc][kk * 32 + lg * 8]);
#pragma unroll
    for (int sub = 0; sub < 4; sub++) {
      bf16x8 afrag = *(const bf16x8*)(woutbf
          + (size_t)(cb + sub * 16 + lc) * HID + kk * 32 + lg * 8);
      oacc[sub] = __builtin_amdgcn_mfma_f32_16x16x32_bf16(afrag, bfrag, oacc[sub], 0, 0, 0);
    }
  }

  float* outb = out + (size_t)b * C_ * N_;
#pragma unroll
  for (int sub = 0; sub < 4; sub++) {
    int co0 = cb + sub * 16 + lg * 4;
    float4 g4 = *(const float4*)(gsws + co0);
    float4 s4 = *(const float4*)(shws + co0);
    outb[(size_t)(co0 + 0) * N_ + n0 + lc] = oacc[sub][0] * g4.x + s4.x;
    outb[(size_t)(co0 + 1) * N_ + n0 + lc] = oacc[sub][1] * g4.y + s4.y;
    outb[(size_t)(co0 + 2) * N_ + n0 + lc] = oacc[sub][2] * g4.z + s4.z;
    outb[(size_t)(co0 + 3) * N_ + n0 + lc] = oacc[sub][3] * g4.w + s4.w;
  }
}

// ---------------------------------------------------------------------------
extern "C" void kernel_launch(void* const* d_in, const int* in_sizes, int n_in,
                              void* d_out, int out_size, void* d_ws, size_t ws_size,
                              hipStream_t stream)
{
  const float* x     = (const float*)d_in[0];
  const float* wq    = (const float*)d_in[1];
  const float* bq    = (const float*)d_in[2];
  const float* wk    = (const float*)d_in[3];
  const float* bk    = (const float*)d_in[4];
  const float* wv    = (const float*)d_in[5];
  const float* bv    = (const float*)d_in[6];
  const float* wfuse = (const float*)d_in[7];
  const float* wout  = (const float*)d_in[8];
  const float* bout  = (const float*)d_in[9];
  const float* gamma = (const float*)d_in[10];
  const float* beta  = (const float*)d_in[11];
  const float* mean  = (const float*)d_in[12];
  const float* var   = (const float*)d_in[13];

  // ws layout (bytes):
  //   [0, 2M)        q  bf16 [2][4][4096][32]
  //   [2M, 4M)       k  bf16 [2][4][4096][32]
  //   [4M, 6M)       vT bf16 [2][4][32][4096]
  //   [6M, +512K)    wbf bf16 [384][512] + woutbf [512][128]
  //   then gsws f32[512], shws f32[512]
  const size_t QK_ELEMS = (size_t)B_ * NH * N_ * DH_;   // 1,048,576
  char* base = (char*)d_ws;
  unsigned short* qws  = (unsigned short*)base;
  unsigned short* kws  = qws + QK_ELEMS;
  unsigned short* vtws = kws + QK_ELEMS;
  unsigned short* wbf  = (unsigned short*)(base + 3 * QK_ELEMS * sizeof(unsigned short));
  unsigned short* woutbf = wbf + 3 * 65536;
  float* gsws = (float*)(wbf + 4 * 65536);
  float* shws = gsws + C_;

  float* out_f  = (float*)d_out;                         // [2][512][4096]
  float* attn_f = out_f + (size_t)B_ * C_ * N_;          // [2][4][4096][4096]

  hipLaunchKernelGGL(prep_w,   dim3(257),  dim3(256), 0, stream,
                     wq, wk, wv, wout, bout, gamma, beta, mean, var,
                     wbf, gsws, shws);
  hipLaunchKernelGGL(qkv_gemm, dim3(768),  dim3(256), 0, stream,
                     wbf, x, bq, bk, bv, qws, kws, vtws);
  hipLaunchKernelGGL(attn_zpv, dim3(512), dim3(512), 0, stream,
                     qws, kws, vtws, wfuse, woutbf, gsws, shws, attn_f, out_f);
}